// Round 1
// baseline (561.477 us; speedup 1.0000x reference)
//
#include <hip/hip_runtime.h>
#include <hip/hip_bf16.h>

// LuongAttention: B=16, Tq=512, Tk=2048, D=1024 (fp32 in/out)
//   dproj = dec @ W^T            [8192,1024]   (bf16x3, BT-form GEMM)
//   score = dproj @ enc^T        [b,512,2048]  (bf16x3, BT-form GEMM, batched)
//   align = softmax(score)       in-place in d_out alignment region
//   ctx   = align @ enc          [b,512,1024]  (bf16, NN-form GEMM, batched)
// wa_bias adds a per-(b,q) constant to score rows -> cancels in softmax; both
// outputs are independent of it, so it is skipped.

typedef float f32x4 __attribute__((ext_vector_type(4)));
typedef __bf16 bf16x8 __attribute__((ext_vector_type(8)));
typedef unsigned short u16x4 __attribute__((ext_vector_type(4)));

__device__ inline unsigned short f2bf(float f) {
    union { float f; unsigned int u; } v; v.f = f;
    unsigned int r = v.u + 0x7fffu + ((v.u >> 16) & 1u);  // RN-even
    return (unsigned short)(r >> 16);
}
__device__ inline float bf2f(unsigned short h) {
    union { unsigned int u; float f; } v; v.u = ((unsigned int)h) << 16; return v.f;
}

// byte offset into a [128 rows][64 ushort] LDS tile, XOR-swizzled on 16B chunks
// (row stride 128B == 32 banks, so swizzle is required for conflict-free b128 reads)
__device__ inline int tile_byte(int row, int kElem) {
    int chunk = kElem >> 3;                       // 0..7 (16B chunks)
    return row * 128 + ((chunk ^ (row & 7)) << 4) + ((kElem & 7) << 1);
}

// C = A @ Bt^T  where A is [M,K] fp32, Bt is [N,K] fp32 (row-major, K contiguous).
// bf16x3: hi*hi + hi*lo + lo*hi  (~fp32 accuracy). Batched via blockIdx.z.
__global__ __launch_bounds__(256, 2)
void gemm_bt_x3(const float* __restrict__ A, long long sA,
                const float* __restrict__ Bt, long long sB,
                float* __restrict__ C, long long sC,
                int M, int N, int K)
{
    __shared__ unsigned short Ah[128 * 64], Al[128 * 64];
    __shared__ unsigned short Bh[128 * 64], Bl[128 * 64];

    const int tid = threadIdx.x, lane = tid & 63, wave = tid >> 6;
    const int wr = (wave >> 1) * 64, wc = (wave & 1) * 64;
    const int bm = blockIdx.y * 128, bn = blockIdx.x * 128;
    A += (size_t)blockIdx.z * sA;
    Bt += (size_t)blockIdx.z * sB;
    C += (size_t)blockIdx.z * sC;

    f32x4 acc[4][4] = {};

    for (int kt = 0; kt < K; kt += 64) {
        // stage 128x64 fp32 tiles of A and Bt, split to bf16 hi/lo
#pragma unroll
        for (int i = 0; i < 8; ++i) {
            int idx = tid + i * 256;
            int row = idx >> 4, f4 = idx & 15;        // 16 float4 per row
            f32x4 va = *reinterpret_cast<const f32x4*>(A + (size_t)(bm + row) * K + kt + f4 * 4);
            f32x4 vb = *reinterpret_cast<const f32x4*>(Bt + (size_t)(bn + row) * K + kt + f4 * 4);
            u16x4 ah, al, bh, bl;
#pragma unroll
            for (int j = 0; j < 4; ++j) {
                unsigned short h = f2bf(va[j]);
                ah[j] = h; al[j] = f2bf(va[j] - bf2f(h));
                h = f2bf(vb[j]);
                bh[j] = h; bl[j] = f2bf(vb[j] - bf2f(h));
            }
            int off = tile_byte(row, f4 * 4);
            *reinterpret_cast<u16x4*>((char*)Ah + off) = ah;
            *reinterpret_cast<u16x4*>((char*)Al + off) = al;
            *reinterpret_cast<u16x4*>((char*)Bh + off) = bh;
            *reinterpret_cast<u16x4*>((char*)Bl + off) = bl;
        }
        __syncthreads();
#pragma unroll
        for (int kk = 0; kk < 2; ++kk) {
            bf16x8 a_h[4], a_l[4], b_h[4], b_l[4];
            const int kbase = kk * 32 + (lane >> 4) * 8;
#pragma unroll
            for (int m = 0; m < 4; ++m) {
                int off = tile_byte(wr + m * 16 + (lane & 15), kbase);
                a_h[m] = *reinterpret_cast<const bf16x8*>((char*)Ah + off);
                a_l[m] = *reinterpret_cast<const bf16x8*>((char*)Al + off);
            }
#pragma unroll
            for (int n = 0; n < 4; ++n) {
                int off = tile_byte(wc + n * 16 + (lane & 15), kbase);
                b_h[n] = *reinterpret_cast<const bf16x8*>((char*)Bh + off);
                b_l[n] = *reinterpret_cast<const bf16x8*>((char*)Bl + off);
            }
#pragma unroll
            for (int m = 0; m < 4; ++m)
#pragma unroll
                for (int n = 0; n < 4; ++n) {
                    acc[m][n] = __builtin_amdgcn_mfma_f32_16x16x32_bf16(a_h[m], b_h[n], acc[m][n], 0, 0, 0);
                    acc[m][n] = __builtin_amdgcn_mfma_f32_16x16x32_bf16(a_h[m], b_l[n], acc[m][n], 0, 0, 0);
                    acc[m][n] = __builtin_amdgcn_mfma_f32_16x16x32_bf16(a_l[m], b_h[n], acc[m][n], 0, 0, 0);
                }
        }
        __syncthreads();
    }
    // epilogue: C/D layout col = lane&15, row = (lane>>4)*4 + j  [HW-verified]
#pragma unroll
    for (int m = 0; m < 4; ++m)
#pragma unroll
        for (int j = 0; j < 4; ++j) {
            int grow = bm + wr + m * 16 + (lane >> 4) * 4 + j;
            float* cr = C + (size_t)grow * N + bn + wc + (lane & 15);
#pragma unroll
            for (int n = 0; n < 4; ++n) cr[n * 16] = acc[m][n][j];
        }
}

// C = A @ Bn  where A is [M,K] fp32, Bn is [K,N] fp32. Single bf16. Batched.
__global__ __launch_bounds__(256, 2)
void gemm_nn_bf16(const float* __restrict__ A, long long sA,
                  const float* __restrict__ Bn, long long sB,
                  float* __restrict__ C, long long sC,
                  int M, int N, int K)
{
    __shared__ unsigned short As[128 * 64];
    __shared__ unsigned short Bs[64 * 130];   // [k][e] +2 pad: conflict-free u16 column reads

    const int tid = threadIdx.x, lane = tid & 63, wave = tid >> 6;
    const int wr = (wave >> 1) * 64, wc = (wave & 1) * 64;
    const int bm = blockIdx.y * 128, bn = blockIdx.x * 128;
    A += (size_t)blockIdx.z * sA;
    Bn += (size_t)blockIdx.z * sB;
    C += (size_t)blockIdx.z * sC;

    f32x4 acc[4][4] = {};

    for (int kt = 0; kt < K; kt += 64) {
        // stage A: 128 rows x 64 k
#pragma unroll
        for (int i = 0; i < 8; ++i) {
            int idx = tid + i * 256;
            int row = idx >> 4, f4 = idx & 15;
            f32x4 va = *reinterpret_cast<const f32x4*>(A + (size_t)(bm + row) * K + kt + f4 * 4);
            u16x4 h;
#pragma unroll
            for (int j = 0; j < 4; ++j) h[j] = f2bf(va[j]);
            *reinterpret_cast<u16x4*>((char*)As + tile_byte(row, f4 * 4)) = h;
        }
        // stage B: 64 k-rows x 128 cols
#pragma unroll
        for (int i = 0; i < 8; ++i) {
            int idx = tid + i * 256;
            int krow = idx >> 5, f4 = idx & 31;
            f32x4 vb = *reinterpret_cast<const f32x4*>(Bn + (size_t)(kt + krow) * N + bn + f4 * 4);
            unsigned int p0 = (unsigned int)f2bf(vb[0]) | ((unsigned int)f2bf(vb[1]) << 16);
            unsigned int p1 = (unsigned int)f2bf(vb[2]) | ((unsigned int)f2bf(vb[3]) << 16);
            unsigned int* bp = reinterpret_cast<unsigned int*>(&Bs[krow * 130 + f4 * 4]);
            bp[0] = p0; bp[1] = p1;
        }
        __syncthreads();
#pragma unroll
        for (int kk = 0; kk < 2; ++kk) {
            bf16x8 a[4], b[4];
            const int kbase = kk * 32 + (lane >> 4) * 8;
#pragma unroll
            for (int m = 0; m < 4; ++m)
                a[m] = *reinterpret_cast<const bf16x8*>((char*)As + tile_byte(wr + m * 16 + (lane & 15), kbase));
#pragma unroll
            for (int n = 0; n < 4; ++n) {
                int col = wc + n * 16 + (lane & 15);
                union { unsigned short u[8]; bf16x8 v; } t;
#pragma unroll
                for (int j = 0; j < 8; ++j) t.u[j] = Bs[(kbase + j) * 130 + col];
                b[n] = t.v;
            }
#pragma unroll
            for (int m = 0; m < 4; ++m)
#pragma unroll
                for (int n = 0; n < 4; ++n)
                    acc[m][n] = __builtin_amdgcn_mfma_f32_16x16x32_bf16(a[m], b[n], acc[m][n], 0, 0, 0);
        }
        __syncthreads();
    }
#pragma unroll
    for (int m = 0; m < 4; ++m)
#pragma unroll
        for (int j = 0; j < 4; ++j) {
            int grow = bm + wr + m * 16 + (lane >> 4) * 4 + j;
            float* cr = C + (size_t)grow * N + bn + wc + (lane & 15);
#pragma unroll
            for (int n = 0; n < 4; ++n) cr[n * 16] = acc[m][n][j];
        }
}

// in-place row softmax over 2048 columns, one block per row
__global__ __launch_bounds__(256)
void softmax_rows(float* __restrict__ P)
{
    __shared__ float redm[4], reds[4];
    float* p = P + (size_t)blockIdx.x * 2048;
    const int tid = threadIdx.x, lane = tid & 63, wave = tid >> 6;

    f32x4 v0 = *reinterpret_cast<const f32x4*>(p + tid * 4);
    f32x4 v1 = *reinterpret_cast<const f32x4*>(p + 1024 + tid * 4);

    float mx = fmaxf(fmaxf(fmaxf(v0[0], v0[1]), fmaxf(v0[2], v0[3])),
                     fmaxf(fmaxf(v1[0], v1[1]), fmaxf(v1[2], v1[3])));
#pragma unroll
    for (int o = 32; o; o >>= 1) mx = fmaxf(mx, __shfl_xor(mx, o));
    if (lane == 0) redm[wave] = mx;
    __syncthreads();
    mx = fmaxf(fmaxf(redm[0], redm[1]), fmaxf(redm[2], redm[3]));

    float s = 0.f;
#pragma unroll
    for (int j = 0; j < 4; ++j) { v0[j] = __expf(v0[j] - mx); s += v0[j]; }
#pragma unroll
    for (int j = 0; j < 4; ++j) { v1[j] = __expf(v1[j] - mx); s += v1[j]; }
#pragma unroll
    for (int o = 32; o; o >>= 1) s += __shfl_xor(s, o);
    if (lane == 0) reds[wave] = s;
    __syncthreads();
    s = reds[0] + reds[1] + reds[2] + reds[3];

    const float inv = 1.0f / s;
#pragma unroll
    for (int j = 0; j < 4; ++j) { v0[j] *= inv; v1[j] *= inv; }
    *reinterpret_cast<f32x4*>(p + tid * 4) = v0;
    *reinterpret_cast<f32x4*>(p + 1024 + tid * 4) = v1;
}

extern "C" void kernel_launch(void* const* d_in, const int* in_sizes, int n_in,
                              void* d_out, int out_size, void* d_ws, size_t ws_size,
                              hipStream_t stream)
{
    (void)in_sizes; (void)n_in; (void)out_size; (void)ws_size;
    const float* dec = (const float*)d_in[0];   // [16,512,1024]
    const float* enc = (const float*)d_in[1];   // [16,2048,1024]
    const float* W   = (const float*)d_in[2];   // [1024,1024]
    // d_in[3] = wa_bias: cancels in softmax, outputs independent of it.

    float* ctx   = (float*)d_out;                            // [16,512,1024]
    float* align = (float*)d_out + (size_t)16 * 512 * 1024;  // [16,512,2048]
    float* dproj = (float*)d_ws;                             // [8192,1024] fp32

    // K1: dproj = dec @ W^T   (M=8192, N=1024, K=1024), one batch
    gemm_bt_x3<<<dim3(8, 64, 1), 256, 0, stream>>>(
        dec, 0, W, 0, dproj, 0, 8192, 1024, 1024);

    // K2: score = dproj @ enc^T  per batch (M=512, N=2048, K=1024) -> align region
    gemm_bt_x3<<<dim3(16, 4, 16), 256, 0, stream>>>(
        dproj, 512LL * 1024, enc, 2048LL * 1024, align, 512LL * 2048, 512, 2048, 1024);

    // K3: softmax rows (8192 rows x 2048)
    softmax_rows<<<8192, 256, 0, stream>>>(align);

    // K4: ctx = align @ enc  per batch (M=512, N=1024, K=2048)
    gemm_nn_bf16<<<dim3(8, 4, 16), 256, 0, stream>>>(
        align, 512LL * 2048, enc, 2048LL * 1024, ctx, 512LL * 1024, 512, 1024, 2048);
}

// Round 2
// 431.800 us; speedup vs baseline: 1.3003x; 1.3003x over previous
//
#include <hip/hip_runtime.h>
#include <hip/hip_bf16.h>

// LuongAttention: B=16, Tq=512, Tk=2048, D=1024 (fp32 in/out)
// Fast path (needs ws >= 160 MiB):
//   P0: split enc/dec/W into bf16 hi/lo planes (elementwise, memory-bound)
//   K1: dproj_h/l = split(dec @ W^T)        pure-bf16 x3 GEMM (global_load_lds)
//   K2: score = dproj @ enc^T -> align area pure-bf16 x3 GEMM
//   K3: softmax in place + bf16 copy (align_b)
//   K4: ctx = align_b @ enc                 bf16-A global_load_lds, fp32-B staging
// Scratch aliasing: dproj_h/l in d_out ctx region (dead until K4 writes);
// dec/W splits in d_out align region (dead until K2 writes). ws: enc_h, enc_l,
// align_b. wa_bias cancels in softmax -> skipped.
// Fallback path (< 160 MiB ws): round-1 kernels (need 32 MiB ws).

typedef float f32x4 __attribute__((ext_vector_type(4)));
typedef __bf16 bf16x8 __attribute__((ext_vector_type(8)));
typedef unsigned short u16x4 __attribute__((ext_vector_type(4)));
typedef unsigned short u16x8 __attribute__((ext_vector_type(8)));

__device__ inline unsigned short f2bf(float f) {
    union { float f; unsigned int u; } v; v.f = f;
    unsigned int r = v.u + 0x7fffu + ((v.u >> 16) & 1u);  // RN-even
    return (unsigned short)(r >> 16);
}
__device__ inline float bf2f(unsigned short h) {
    union { unsigned int u; float f; } v; v.u = ((unsigned int)h) << 16; return v.f;
}

__device__ inline void gload16(const void* g, const void* l) {
    __builtin_amdgcn_global_load_lds(
        (const __attribute__((address_space(1))) unsigned int*)g,
        (__attribute__((address_space(3))) unsigned int*)l, 16, 0, 0);
}

// ---------------- P0: fp32 -> bf16 hi/lo split (elementwise) ----------------
__global__ __launch_bounds__(256)
void split_bf16(const float* __restrict__ x, unsigned short* __restrict__ ho,
                unsigned short* __restrict__ lo, int n8)
{
    int i = blockIdx.x * 256 + threadIdx.x;
    if (i >= n8) return;
    const f32x4* xp = reinterpret_cast<const f32x4*>(x + (size_t)i * 8);
    f32x4 v0 = xp[0], v1 = xp[1];
    u16x8 h, l;
#pragma unroll
    for (int j = 0; j < 4; ++j) {
        unsigned short hh = f2bf(v0[j]);
        h[j] = hh; l[j] = f2bf(v0[j] - bf2f(hh));
        hh = f2bf(v1[j]);
        h[4 + j] = hh; l[4 + j] = f2bf(v1[j] - bf2f(hh));
    }
    *reinterpret_cast<u16x8*>(ho + (size_t)i * 8) = h;
    *reinterpret_cast<u16x8*>(lo + (size_t)i * 8) = l;
}

// ------------- pure-bf16 x3 BT GEMM: C = (Ah+Al) @ (Bh+Bl)^T ----------------
// A planes [M,K], B planes [N,K] bf16, K%32==0. BK=32, tile 128x128, 4 waves.
// LDS linear (global_load_lds) with pre-swizzled source: slot s at (row)
// holds global chunk kc = s ^ ((row>>2)&3); read applies the same XOR.
// OUTMODE 0: fp32 C.  OUTMODE 1: bf16 hi/lo split -> Ch, Cl.
template<int OUTMODE>
__global__ __launch_bounds__(256, 2)
void gemm_bt3_bf16(const unsigned short* __restrict__ Ah, const unsigned short* __restrict__ Al,
                   long long sA,
                   const unsigned short* __restrict__ Bh, const unsigned short* __restrict__ Bl,
                   long long sB,
                   float* __restrict__ C, unsigned short* __restrict__ Ch,
                   unsigned short* __restrict__ Cl, long long sC,
                   int M, int N, int K)
{
    __shared__ unsigned short LAh[128 * 32], LAl[128 * 32];
    __shared__ unsigned short LBh[128 * 32], LBl[128 * 32];

    const int tid = threadIdx.x, lane = tid & 63, wave = tid >> 6;
    const int wr = (wave >> 1) * 64, wc = (wave & 1) * 64;
    const int bm = blockIdx.y * 128, bn = blockIdx.x * 128;
    Ah += (size_t)blockIdx.z * sA; Al += (size_t)blockIdx.z * sA;
    Bh += (size_t)blockIdx.z * sB; Bl += (size_t)blockIdx.z * sB;

    f32x4 acc[4][4] = {};

    // per-thread staging geometry (2 wave-calls per plane)
    int cid0 = wave * 128 + lane;        // c=0
    int cid1 = wave * 128 + 64 + lane;   // c=1
    int r0 = cid0 >> 2, kc0 = (cid0 & 3) ^ ((r0 >> 2) & 3);
    int r1 = cid1 >> 2, kc1 = (cid1 & 3) ^ ((r1 >> 2) & 3);
    int lb0 = (wave * 2 + 0) * 512;      // u16 elements, wave-uniform
    int lb1 = (wave * 2 + 1) * 512;

    const int kcL = lane >> 4;           // logical k-chunk 0..3
    const int fr = lane & 15;

    for (int kt = 0; kt < K; kt += 32) {
        gload16(Ah + (size_t)(bm + r0) * K + kt + kc0 * 8, LAh + lb0);
        gload16(Ah + (size_t)(bm + r1) * K + kt + kc1 * 8, LAh + lb1);
        gload16(Al + (size_t)(bm + r0) * K + kt + kc0 * 8, LAl + lb0);
        gload16(Al + (size_t)(bm + r1) * K + kt + kc1 * 8, LAl + lb1);
        gload16(Bh + (size_t)(bn + r0) * K + kt + kc0 * 8, LBh + lb0);
        gload16(Bh + (size_t)(bn + r1) * K + kt + kc1 * 8, LBh + lb1);
        gload16(Bl + (size_t)(bn + r0) * K + kt + kc0 * 8, LBl + lb0);
        gload16(Bl + (size_t)(bn + r1) * K + kt + kc1 * 8, LBl + lb1);
        __syncthreads();

        bf16x8 bh[4], bl[4];
#pragma unroll
        for (int n = 0; n < 4; ++n) {
            int row = wc + n * 16 + fr;
            int off = row * 32 + ((kcL ^ ((row >> 2) & 3)) << 3);
            bh[n] = *reinterpret_cast<const bf16x8*>(LBh + off);
            bl[n] = *reinterpret_cast<const bf16x8*>(LBl + off);
        }
#pragma unroll
        for (int m = 0; m < 4; ++m) {
            int row = wr + m * 16 + fr;
            int off = row * 32 + ((kcL ^ ((row >> 2) & 3)) << 3);
            bf16x8 ah = *reinterpret_cast<const bf16x8*>(LAh + off);
            bf16x8 al = *reinterpret_cast<const bf16x8*>(LAl + off);
#pragma unroll
            for (int n = 0; n < 4; ++n) {
                acc[m][n] = __builtin_amdgcn_mfma_f32_16x16x32_bf16(ah, bh[n], acc[m][n], 0, 0, 0);
                acc[m][n] = __builtin_amdgcn_mfma_f32_16x16x32_bf16(ah, bl[n], acc[m][n], 0, 0, 0);
                acc[m][n] = __builtin_amdgcn_mfma_f32_16x16x32_bf16(al, bh[n], acc[m][n], 0, 0, 0);
            }
        }
        __syncthreads();
    }

    // C/D layout: col = lane&15, row = (lane>>4)*4 + j  [HW-verified]
    if (OUTMODE == 0) {
        C += (size_t)blockIdx.z * sC;
#pragma unroll
        for (int m = 0; m < 4; ++m)
#pragma unroll
            for (int j = 0; j < 4; ++j) {
                int grow = bm + wr + m * 16 + (lane >> 4) * 4 + j;
                float* cr = C + (size_t)grow * N + bn + wc + fr;
#pragma unroll
                for (int n = 0; n < 4; ++n) cr[n * 16] = acc[m][n][j];
            }
    } else {
        Ch += (size_t)blockIdx.z * sC; Cl += (size_t)blockIdx.z * sC;
#pragma unroll
        for (int m = 0; m < 4; ++m)
#pragma unroll
            for (int j = 0; j < 4; ++j) {
                int grow = bm + wr + m * 16 + (lane >> 4) * 4 + j;
                size_t rb = (size_t)grow * N + bn + wc + fr;
#pragma unroll
                for (int n = 0; n < 4; ++n) {
                    float v = acc[m][n][j];
                    unsigned short hh = f2bf(v);
                    Ch[rb + n * 16] = hh;
                    Cl[rb + n * 16] = f2bf(v - bf2f(hh));
                }
            }
    }
}

// -------- K4 fast: C = Ab(bf16,[M,K]) @ Bn(fp32,[K,N]), single bf16 ---------
__global__ __launch_bounds__(256, 2)
void gemm_nn_fastA(const unsigned short* __restrict__ Ab, long long sA,
                   const float* __restrict__ Bn, long long sB,
                   float* __restrict__ C, long long sC,
                   int M, int N, int K)
{
    __shared__ unsigned short As[128 * 64];
    __shared__ unsigned short Bs[64 * 130];

    const int tid = threadIdx.x, lane = tid & 63, wave = tid >> 6;
    const int wr = (wave >> 1) * 64, wc = (wave & 1) * 64;
    const int bm = blockIdx.y * 128, bn = blockIdx.x * 128;
    Ab += (size_t)blockIdx.z * sA;
    Bn += (size_t)blockIdx.z * sB;
    C += (size_t)blockIdx.z * sC;

    f32x4 acc[4][4] = {};

    for (int kt = 0; kt < K; kt += 64) {
        // A: global_load_lds, linear LDS + pre-swizzled source (8 chunks/row)
#pragma unroll
        for (int c = 0; c < 4; ++c) {
            int cid = (wave * 4 + c) * 64 + lane;
            int row = cid >> 3;
            int kc = (cid & 7) ^ (row & 7);
            gload16(Ab + (size_t)(bm + row) * K + kt + kc * 8, As + (wave * 4 + c) * 512);
        }
        // B: fp32 -> bf16 convert staging into padded [k][col] tile
#pragma unroll
        for (int i = 0; i < 8; ++i) {
            int idx = tid + i * 256;
            int krow = idx >> 5, f4 = idx & 31;
            f32x4 vb = *reinterpret_cast<const f32x4*>(Bn + (size_t)(kt + krow) * N + bn + f4 * 4);
            unsigned int p0 = (unsigned int)f2bf(vb[0]) | ((unsigned int)f2bf(vb[1]) << 16);
            unsigned int p1 = (unsigned int)f2bf(vb[2]) | ((unsigned int)f2bf(vb[3]) << 16);
            unsigned int* bp = reinterpret_cast<unsigned int*>(&Bs[krow * 130 + f4 * 4]);
            bp[0] = p0; bp[1] = p1;
        }
        __syncthreads();
#pragma unroll
        for (int kk = 0; kk < 2; ++kk) {
            const int kbase = kk * 32 + (lane >> 4) * 8;
            const int chunk = kbase >> 3;
            bf16x8 a[4], b[4];
#pragma unroll
            for (int m = 0; m < 4; ++m) {
                int row = wr + m * 16 + (lane & 15);
                a[m] = *reinterpret_cast<const bf16x8*>(As + row * 64 + ((chunk ^ (row & 7)) << 3));
            }
#pragma unroll
            for (int n = 0; n < 4; ++n) {
                int col = wc + n * 16 + (lane & 15);
                union { unsigned short u[8]; bf16x8 v; } t;
#pragma unroll
                for (int j = 0; j < 8; ++j) t.u[j] = Bs[(kbase + j) * 130 + col];
                b[n] = t.v;
            }
#pragma unroll
            for (int m = 0; m < 4; ++m)
#pragma unroll
                for (int n = 0; n < 4; ++n)
                    acc[m][n] = __builtin_amdgcn_mfma_f32_16x16x32_bf16(a[m], b[n], acc[m][n], 0, 0, 0);
        }
        __syncthreads();
    }
#pragma unroll
    for (int m = 0; m < 4; ++m)
#pragma unroll
        for (int j = 0; j < 4; ++j) {
            int grow = bm + wr + m * 16 + (lane >> 4) * 4 + j;
            float* cr = C + (size_t)grow * N + bn + wc + (lane & 15);
#pragma unroll
            for (int n = 0; n < 4; ++n) cr[n * 16] = acc[m][n][j];
        }
}

// ---------------- softmax rows (2048 cols) + optional bf16 copy -------------
__global__ __launch_bounds__(256)
void softmax_rows(float* __restrict__ P, unsigned short* __restrict__ albf)
{
    __shared__ float redm[4], reds[4];
    float* p = P + (size_t)blockIdx.x * 2048;
    const int tid = threadIdx.x, lane = tid & 63, wave = tid >> 6;

    f32x4 v0 = *reinterpret_cast<const f32x4*>(p + tid * 4);
    f32x4 v1 = *reinterpret_cast<const f32x4*>(p + 1024 + tid * 4);

    float mx = fmaxf(fmaxf(fmaxf(v0[0], v0[1]), fmaxf(v0[2], v0[3])),
                     fmaxf(fmaxf(v1[0], v1[1]), fmaxf(v1[2], v1[3])));
#pragma unroll
    for (int o = 32; o; o >>= 1) mx = fmaxf(mx, __shfl_xor(mx, o));
    if (lane == 0) redm[wave] = mx;
    __syncthreads();
    mx = fmaxf(fmaxf(redm[0], redm[1]), fmaxf(redm[2], redm[3]));

    float s = 0.f;
#pragma unroll
    for (int j = 0; j < 4; ++j) { v0[j] = __expf(v0[j] - mx); s += v0[j]; }
#pragma unroll
    for (int j = 0; j < 4; ++j) { v1[j] = __expf(v1[j] - mx); s += v1[j]; }
#pragma unroll
    for (int o = 32; o; o >>= 1) s += __shfl_xor(s, o);
    if (lane == 0) reds[wave] = s;
    __syncthreads();
    s = reds[0] + reds[1] + reds[2] + reds[3];

    const float inv = 1.0f / s;
#pragma unroll
    for (int j = 0; j < 4; ++j) { v0[j] *= inv; v1[j] *= inv; }
    *reinterpret_cast<f32x4*>(p + tid * 4) = v0;
    *reinterpret_cast<f32x4*>(p + 1024 + tid * 4) = v1;

    if (albf) {
        unsigned short* ab = albf + (size_t)blockIdx.x * 2048;
        u16x4 h0, h1;
#pragma unroll
        for (int j = 0; j < 4; ++j) { h0[j] = f2bf(v0[j]); h1[j] = f2bf(v1[j]); }
        *reinterpret_cast<u16x4*>(ab + tid * 4) = h0;
        *reinterpret_cast<u16x4*>(ab + 1024 + tid * 4) = h1;
    }
}

// ======================= round-1 fallback kernels ===========================
__device__ inline int tile_byte(int row, int kElem) {
    int chunk = kElem >> 3;
    return row * 128 + ((chunk ^ (row & 7)) << 4) + ((kElem & 7) << 1);
}

__global__ __launch_bounds__(256, 2)
void gemm_bt_x3(const float* __restrict__ A, long long sA,
                const float* __restrict__ Bt, long long sB,
                float* __restrict__ C, long long sC,
                int M, int N, int K)
{
    __shared__ unsigned short Ah[128 * 64], Al[128 * 64];
    __shared__ unsigned short Bh[128 * 64], Bl[128 * 64];

    const int tid = threadIdx.x, lane = tid & 63, wave = tid >> 6;
    const int wr = (wave >> 1) * 64, wc = (wave & 1) * 64;
    const int bm = blockIdx.y * 128, bn = blockIdx.x * 128;
    A += (size_t)blockIdx.z * sA;
    Bt += (size_t)blockIdx.z * sB;
    C += (size_t)blockIdx.z * sC;

    f32x4 acc[4][4] = {};

    for (int kt = 0; kt < K; kt += 64) {
#pragma unroll
        for (int i = 0; i < 8; ++i) {
            int idx = tid + i * 256;
            int row = idx >> 4, f4 = idx & 15;
            f32x4 va = *reinterpret_cast<const f32x4*>(A + (size_t)(bm + row) * K + kt + f4 * 4);
            f32x4 vb = *reinterpret_cast<const f32x4*>(Bt + (size_t)(bn + row) * K + kt + f4 * 4);
            u16x4 ah, al, bh, bl;
#pragma unroll
            for (int j = 0; j < 4; ++j) {
                unsigned short h = f2bf(va[j]);
                ah[j] = h; al[j] = f2bf(va[j] - bf2f(h));
                h = f2bf(vb[j]);
                bh[j] = h; bl[j] = f2bf(vb[j] - bf2f(h));
            }
            int off = tile_byte(row, f4 * 4);
            *reinterpret_cast<u16x4*>((char*)Ah + off) = ah;
            *reinterpret_cast<u16x4*>((char*)Al + off) = al;
            *reinterpret_cast<u16x4*>((char*)Bh + off) = bh;
            *reinterpret_cast<u16x4*>((char*)Bl + off) = bl;
        }
        __syncthreads();
#pragma unroll
        for (int kk = 0; kk < 2; ++kk) {
            bf16x8 a_h[4], a_l[4], b_h[4], b_l[4];
            const int kbase = kk * 32 + (lane >> 4) * 8;
#pragma unroll
            for (int m = 0; m < 4; ++m) {
                int off = tile_byte(wr + m * 16 + (lane & 15), kbase);
                a_h[m] = *reinterpret_cast<const bf16x8*>((char*)Ah + off);
                a_l[m] = *reinterpret_cast<const bf16x8*>((char*)Al + off);
            }
#pragma unroll
            for (int n = 0; n < 4; ++n) {
                int off = tile_byte(wc + n * 16 + (lane & 15), kbase);
                b_h[n] = *reinterpret_cast<const bf16x8*>((char*)Bh + off);
                b_l[n] = *reinterpret_cast<const bf16x8*>((char*)Bl + off);
            }
#pragma unroll
            for (int m = 0; m < 4; ++m)
#pragma unroll
                for (int n = 0; n < 4; ++n) {
                    acc[m][n] = __builtin_amdgcn_mfma_f32_16x16x32_bf16(a_h[m], b_h[n], acc[m][n], 0, 0, 0);
                    acc[m][n] = __builtin_amdgcn_mfma_f32_16x16x32_bf16(a_h[m], b_l[n], acc[m][n], 0, 0, 0);
                    acc[m][n] = __builtin_amdgcn_mfma_f32_16x16x32_bf16(a_l[m], b_h[n], acc[m][n], 0, 0, 0);
                }
        }
        __syncthreads();
    }
#pragma unroll
    for (int m = 0; m < 4; ++m)
#pragma unroll
        for (int j = 0; j < 4; ++j) {
            int grow = bm + wr + m * 16 + (lane >> 4) * 4 + j;
            float* cr = C + (size_t)grow * N + bn + wc + (lane & 15);
#pragma unroll
            for (int n = 0; n < 4; ++n) cr[n * 16] = acc[m][n][j];
        }
}

__global__ __launch_bounds__(256, 2)
void gemm_nn_bf16(const float* __restrict__ A, long long sA,
                  const float* __restrict__ Bn, long long sB,
                  float* __restrict__ C, long long sC,
                  int M, int N, int K)
{
    __shared__ unsigned short As[128 * 64];
    __shared__ unsigned short Bs[64 * 130];

    const int tid = threadIdx.x, lane = tid & 63, wave = tid >> 6;
    const int wr = (wave >> 1) * 64, wc = (wave & 1) * 64;
    const int bm = blockIdx.y * 128, bn = blockIdx.x * 128;
    A += (size_t)blockIdx.z * sA;
    Bn += (size_t)blockIdx.z * sB;
    C += (size_t)blockIdx.z * sC;

    f32x4 acc[4][4] = {};

    for (int kt = 0; kt < K; kt += 64) {
#pragma unroll
        for (int i = 0; i < 8; ++i) {
            int idx = tid + i * 256;
            int row = idx >> 4, f4 = idx & 15;
            f32x4 va = *reinterpret_cast<const f32x4*>(A + (size_t)(bm + row) * K + kt + f4 * 4);
            u16x4 h;
#pragma unroll
            for (int j = 0; j < 4; ++j) h[j] = f2bf(va[j]);
            *reinterpret_cast<u16x4*>((char*)As + tile_byte(row, f4 * 4)) = h;
        }
#pragma unroll
        for (int i = 0; i < 8; ++i) {
            int idx = tid + i * 256;
            int krow = idx >> 5, f4 = idx & 31;
            f32x4 vb = *reinterpret_cast<const f32x4*>(Bn + (size_t)(kt + krow) * N + bn + f4 * 4);
            unsigned int p0 = (unsigned int)f2bf(vb[0]) | ((unsigned int)f2bf(vb[1]) << 16);
            unsigned int p1 = (unsigned int)f2bf(vb[2]) | ((unsigned int)f2bf(vb[3]) << 16);
            unsigned int* bp = reinterpret_cast<unsigned int*>(&Bs[krow * 130 + f4 * 4]);
            bp[0] = p0; bp[1] = p1;
        }
        __syncthreads();
#pragma unroll
        for (int kk = 0; kk < 2; ++kk) {
            bf16x8 a[4], b[4];
            const int kbase = kk * 32 + (lane >> 4) * 8;
#pragma unroll
            for (int m = 0; m < 4; ++m)
                a[m] = *reinterpret_cast<const bf16x8*>((char*)As + tile_byte(wr + m * 16 + (lane & 15), kbase));
#pragma unroll
            for (int n = 0; n < 4; ++n) {
                int col = wc + n * 16 + (lane & 15);
                union { unsigned short u[8]; bf16x8 v; } t;
#pragma unroll
                for (int j = 0; j < 8; ++j) t.u[j] = Bs[(kbase + j) * 130 + col];
                b[n] = t.v;
            }
#pragma unroll
            for (int m = 0; m < 4; ++m)
#pragma unroll
                for (int n = 0; n < 4; ++n)
                    acc[m][n] = __builtin_amdgcn_mfma_f32_16x16x32_bf16(a[m], b[n], acc[m][n], 0, 0, 0);
        }
        __syncthreads();
    }
#pragma unroll
    for (int m = 0; m < 4; ++m)
#pragma unroll
        for (int j = 0; j < 4; ++j) {
            int grow = bm + wr + m * 16 + (lane >> 4) * 4 + j;
            float* cr = C + (size_t)grow * N + bn + wc + (lane & 15);
#pragma unroll
            for (int n = 0; n < 4; ++n) cr[n * 16] = acc[m][n][j];
        }
}

// ============================================================================
extern "C" void kernel_launch(void* const* d_in, const int* in_sizes, int n_in,
                              void* d_out, int out_size, void* d_ws, size_t ws_size,
                              hipStream_t stream)
{
    (void)in_sizes; (void)n_in; (void)out_size;
    const float* dec = (const float*)d_in[0];   // [16,512,1024]
    const float* enc = (const float*)d_in[1];   // [16,2048,1024]
    const float* W   = (const float*)d_in[2];   // [1024,1024]

    float* ctx   = (float*)d_out;                            // [16,512,1024]
    float* align = (float*)d_out + (size_t)16 * 512 * 1024;  // [16,512,2048]

    const size_t NEED_FAST = (size_t)(33554432ULL * 2 + 16777216ULL) * 2;  // 160 MiB

    if (ws_size >= NEED_FAST) {
        // scratch aliases
        unsigned short* enc_h   = (unsigned short*)d_ws;             // 64 MiB
        unsigned short* enc_l   = enc_h + 33554432ULL;               // 64 MiB
        unsigned short* align_b = enc_l + 33554432ULL;               // 32 MiB
        unsigned short* dproj_h = (unsigned short*)d_out;            // ctx region (dead)
        unsigned short* dproj_l = dproj_h + 8388608ULL;
        unsigned short* dec_h   = (unsigned short*)align;            // align region (dead)
        unsigned short* dec_l   = dec_h + 8388608ULL;
        unsigned short* W_h     = dec_l + 8388608ULL;
        unsigned short* W_l     = W_h + 1048576ULL;

        // P0: splits
        split_bf16<<<16384, 256, 0, stream>>>(enc, enc_h, enc_l, 4194304);
        split_bf16<<<4096, 256, 0, stream>>>(dec, dec_h, dec_l, 1048576);
        split_bf16<<<512, 256, 0, stream>>>(W, W_h, W_l, 131072);

        // K1: dproj = dec @ W^T  (M=8192, N=1024, K=1024) -> bf16 split planes
        gemm_bt3_bf16<1><<<dim3(8, 64, 1), 256, 0, stream>>>(
            dec_h, dec_l, 0, W_h, W_l, 0,
            nullptr, dproj_h, dproj_l, 0, 8192, 1024, 1024);

        // K2: score = dproj @ enc^T per batch (M=512, N=2048, K=1024) -> align
        gemm_bt3_bf16<0><<<dim3(16, 4, 16), 256, 0, stream>>>(
            dproj_h, dproj_l, 512LL * 1024, enc_h, enc_l, 2048LL * 1024,
            align, nullptr, nullptr, 512LL * 2048, 512, 2048, 1024);

        // K3: softmax + bf16 copy
        softmax_rows<<<8192, 256, 0, stream>>>(align, align_b);

        // K4: ctx = align_b @ enc per batch (M=512, N=1024, K=2048)
        gemm_nn_fastA<<<dim3(8, 4, 16), 256, 0, stream>>>(
            align_b, 512LL * 2048, enc, 2048LL * 1024, ctx, 512LL * 1024,
            512, 1024, 2048);
    } else {
        // round-1 fallback (needs 32 MiB ws)
        float* dproj = (float*)d_ws;
        gemm_bt_x3<<<dim3(8, 64, 1), 256, 0, stream>>>(
            dec, 0, W, 0, dproj, 0, 8192, 1024, 1024);
        gemm_bt_x3<<<dim3(16, 4, 16), 256, 0, stream>>>(
            dproj, 512LL * 1024, enc, 2048LL * 1024, align, 512LL * 2048, 512, 2048, 1024);
        softmax_rows<<<8192, 256, 0, stream>>>(align, nullptr);
        gemm_nn_bf16<<<dim3(8, 4, 16), 256, 0, stream>>>(
            align, 512LL * 2048, enc, 2048LL * 1024, ctx, 512LL * 1024, 512, 1024, 2048);
    }
}

// Round 3
// 339.668 us; speedup vs baseline: 1.6530x; 1.2712x over previous
//
#include <hip/hip_runtime.h>
#include <hip/hip_bf16.h>

// LuongAttention: B=16, Tq=512, Tk=2048, D=1024 (fp32 in/out)
// Fast path (needs ws >= 160 MiB):
//   P0: split enc/dec/W into bf16 hi/lo planes (elementwise, memory-bound)
//   K1: dproj_h/l = split(dec @ W^T)        pure-bf16 x3 BT GEMM (global_load_lds)
//   K2: score = dproj @ enc^T -> align area pure-bf16 x3 BT GEMM
//   T:  encT = transpose(enc_h)             bf16 LDS tile transpose (into enc_l region)
//   K3: softmax in place + bf16 copy (align_b)
//   K4: ctx = align_b @ encT^T              pure-bf16 x1 BT GEMM (global_load_lds)
// Scratch aliasing: dproj_h/l in d_out ctx region (dead until K4 writes);
// dec/W splits in d_out align region (dead until K2 writes); encT over enc_l
// (dead after K2). ws: enc_h, enc_l/encT, align_b. wa_bias cancels in softmax.
// Fallback path (< 160 MiB ws): round-1 kernels (need 32 MiB ws).

typedef float f32x4 __attribute__((ext_vector_type(4)));
typedef __bf16 bf16x8 __attribute__((ext_vector_type(8)));
typedef unsigned short u16x4 __attribute__((ext_vector_type(4)));
typedef unsigned short u16x8 __attribute__((ext_vector_type(8)));

__device__ inline unsigned short f2bf(float f) {
    union { float f; unsigned int u; } v; v.f = f;
    unsigned int r = v.u + 0x7fffu + ((v.u >> 16) & 1u);  // RN-even
    return (unsigned short)(r >> 16);
}
__device__ inline float bf2f(unsigned short h) {
    union { unsigned int u; float f; } v; v.u = ((unsigned int)h) << 16; return v.f;
}

__device__ inline void gload16(const void* g, const void* l) {
    __builtin_amdgcn_global_load_lds(
        (const __attribute__((address_space(1))) unsigned int*)g,
        (__attribute__((address_space(3))) unsigned int*)l, 16, 0, 0);
}

// ---------------- P0: fp32 -> bf16 hi/lo split (elementwise) ----------------
__global__ __launch_bounds__(256)
void split_bf16(const float* __restrict__ x, unsigned short* __restrict__ ho,
                unsigned short* __restrict__ lo, int n8)
{
    int i = blockIdx.x * 256 + threadIdx.x;
    if (i >= n8) return;
    const f32x4* xp = reinterpret_cast<const f32x4*>(x + (size_t)i * 8);
    f32x4 v0 = xp[0], v1 = xp[1];
    u16x8 h, l;
#pragma unroll
    for (int j = 0; j < 4; ++j) {
        unsigned short hh = f2bf(v0[j]);
        h[j] = hh; l[j] = f2bf(v0[j] - bf2f(hh));
        hh = f2bf(v1[j]);
        h[4 + j] = hh; l[4 + j] = f2bf(v1[j] - bf2f(hh));
    }
    *reinterpret_cast<u16x8*>(ho + (size_t)i * 8) = h;
    *reinterpret_cast<u16x8*>(lo + (size_t)i * 8) = l;
}

// ------- T: bf16 transpose  in [16][2048][1024] -> out [16][1024][2048] -----
__global__ __launch_bounds__(256)
void transpose_bf16(const unsigned short* __restrict__ in, unsigned short* __restrict__ out)
{
    __shared__ unsigned short t[64][65];
    const int b = blockIdx.z;
    const int kb = blockIdx.x * 64;   // k dim (2048)
    const int db = blockIdx.y * 64;   // d dim (1024)
    const unsigned short* ip = in + ((size_t)b * 2048 + kb) * 1024 + db;
    unsigned short* op = out + ((size_t)b * 1024 + db) * 2048 + kb;
    const int r = threadIdx.x >> 3;         // 0..31
    const int c0 = (threadIdx.x & 7) * 8;
#pragma unroll
    for (int h = 0; h < 2; ++h) {
        u16x8 v = *reinterpret_cast<const u16x8*>(ip + (size_t)(r + h * 32) * 1024 + c0);
#pragma unroll
        for (int j = 0; j < 8; ++j) t[c0 + j][r + h * 32] = v[j];
    }
    __syncthreads();
#pragma unroll
    for (int h = 0; h < 2; ++h) {
        int orow = r + h * 32;
        u16x8 v = *reinterpret_cast<const u16x8*>(&t[orow][c0]);
        *reinterpret_cast<u16x8*>(op + (size_t)orow * 2048 + c0) = v;
    }
}

// ------------- pure-bf16 x3 BT GEMM: C = (Ah+Al) @ (Bh+Bl)^T ----------------
// A planes [M,K], B planes [N,K] bf16, K%32==0. BK=32, tile 128x128, 4 waves.
// LDS linear (global_load_lds) with pre-swizzled source: slot s at (row)
// holds global chunk kc = s ^ ((row>>2)&3); read applies the same XOR.
// OUTMODE 0: fp32 C.  OUTMODE 1: bf16 hi/lo split -> Ch, Cl.
template<int OUTMODE>
__global__ __launch_bounds__(256, 3)
void gemm_bt3_bf16(const unsigned short* __restrict__ Ah, const unsigned short* __restrict__ Al,
                   long long sA,
                   const unsigned short* __restrict__ Bh, const unsigned short* __restrict__ Bl,
                   long long sB,
                   float* __restrict__ C, unsigned short* __restrict__ Ch,
                   unsigned short* __restrict__ Cl, long long sC,
                   int M, int N, int K)
{
    __shared__ unsigned short LAh[128 * 32], LAl[128 * 32];
    __shared__ unsigned short LBh[128 * 32], LBl[128 * 32];

    const int tid = threadIdx.x, lane = tid & 63, wave = tid >> 6;
    const int wr = (wave >> 1) * 64, wc = (wave & 1) * 64;
    const int bm = blockIdx.y * 128, bn = blockIdx.x * 128;
    Ah += (size_t)blockIdx.z * sA; Al += (size_t)blockIdx.z * sA;
    Bh += (size_t)blockIdx.z * sB; Bl += (size_t)blockIdx.z * sB;

    f32x4 acc[4][4] = {};

    int cid0 = wave * 128 + lane;
    int cid1 = wave * 128 + 64 + lane;
    int r0 = cid0 >> 2, kc0 = (cid0 & 3) ^ ((r0 >> 2) & 3);
    int r1 = cid1 >> 2, kc1 = (cid1 & 3) ^ ((r1 >> 2) & 3);
    int lb0 = (wave * 2 + 0) * 512;
    int lb1 = (wave * 2 + 1) * 512;

    const int kcL = lane >> 4;
    const int fr = lane & 15;

    for (int kt = 0; kt < K; kt += 32) {
        gload16(Ah + (size_t)(bm + r0) * K + kt + kc0 * 8, LAh + lb0);
        gload16(Ah + (size_t)(bm + r1) * K + kt + kc1 * 8, LAh + lb1);
        gload16(Al + (size_t)(bm + r0) * K + kt + kc0 * 8, LAl + lb0);
        gload16(Al + (size_t)(bm + r1) * K + kt + kc1 * 8, LAl + lb1);
        gload16(Bh + (size_t)(bn + r0) * K + kt + kc0 * 8, LBh + lb0);
        gload16(Bh + (size_t)(bn + r1) * K + kt + kc1 * 8, LBh + lb1);
        gload16(Bl + (size_t)(bn + r0) * K + kt + kc0 * 8, LBl + lb0);
        gload16(Bl + (size_t)(bn + r1) * K + kt + kc1 * 8, LBl + lb1);
        __syncthreads();

        bf16x8 bh[4], bl[4];
#pragma unroll
        for (int n = 0; n < 4; ++n) {
            int row = wc + n * 16 + fr;
            int off = row * 32 + ((kcL ^ ((row >> 2) & 3)) << 3);
            bh[n] = *reinterpret_cast<const bf16x8*>(LBh + off);
            bl[n] = *reinterpret_cast<const bf16x8*>(LBl + off);
        }
#pragma unroll
        for (int m = 0; m < 4; ++m) {
            int row = wr + m * 16 + fr;
            int off = row * 32 + ((kcL ^ ((row >> 2) & 3)) << 3);
            bf16x8 ah = *reinterpret_cast<const bf16x8*>(LAh + off);
            bf16x8 al = *reinterpret_cast<const bf16x8*>(LAl + off);
#pragma unroll
            for (int n = 0; n < 4; ++n) {
                acc[m][n] = __builtin_amdgcn_mfma_f32_16x16x32_bf16(ah, bh[n], acc[m][n], 0, 0, 0);
                acc[m][n] = __builtin_amdgcn_mfma_f32_16x16x32_bf16(ah, bl[n], acc[m][n], 0, 0, 0);
                acc[m][n] = __builtin_amdgcn_mfma_f32_16x16x32_bf16(al, bh[n], acc[m][n], 0, 0, 0);
            }
        }
        __syncthreads();
    }

    // C/D layout: col = lane&15, row = (lane>>4)*4 + j  [HW-verified]
    if (OUTMODE == 0) {
        C += (size_t)blockIdx.z * sC;
#pragma unroll
        for (int m = 0; m < 4; ++m)
#pragma unroll
            for (int j = 0; j < 4; ++j) {
                int grow = bm + wr + m * 16 + (lane >> 4) * 4 + j;
                float* cr = C + (size_t)grow * N + bn + wc + fr;
#pragma unroll
                for (int n = 0; n < 4; ++n) cr[n * 16] = acc[m][n][j];
            }
    } else {
        Ch += (size_t)blockIdx.z * sC; Cl += (size_t)blockIdx.z * sC;
#pragma unroll
        for (int m = 0; m < 4; ++m)
#pragma unroll
            for (int j = 0; j < 4; ++j) {
                int grow = bm + wr + m * 16 + (lane >> 4) * 4 + j;
                size_t rb = (size_t)grow * N + bn + wc + fr;
#pragma unroll
                for (int n = 0; n < 4; ++n) {
                    float v = acc[m][n][j];
                    unsigned short hh = f2bf(v);
                    Ch[rb + n * 16] = hh;
                    Cl[rb + n * 16] = f2bf(v - bf2f(hh));
                }
            }
    }
}

// ---------- K4: pure-bf16 x1 BT GEMM: C = A @ Bt^T, BK=64 -------------------
// A [M,K], Bt [N,K] bf16. LDS linear via global_load_lds, 8-chunk XOR swizzle.
__global__ __launch_bounds__(256, 3)
void gemm_bt_bf16(const unsigned short* __restrict__ A, long long sA,
                  const unsigned short* __restrict__ Bt, long long sB,
                  float* __restrict__ C, long long sC,
                  int M, int N, int K)
{
    __shared__ unsigned short LA[128 * 64], LB[128 * 64];

    const int tid = threadIdx.x, lane = tid & 63, wave = tid >> 6;
    const int wr = (wave >> 1) * 64, wc = (wave & 1) * 64;
    const int bm = blockIdx.y * 128, bn = blockIdx.x * 128;
    A += (size_t)blockIdx.z * sA;
    Bt += (size_t)blockIdx.z * sB;
    C += (size_t)blockIdx.z * sC;

    f32x4 acc[4][4] = {};

    const int fr = lane & 15;

    for (int kt = 0; kt < K; kt += 64) {
#pragma unroll
        for (int c = 0; c < 4; ++c) {
            int cid = (wave * 4 + c) * 64 + lane;    // 0..1023
            int row = cid >> 3;
            int kc = (cid & 7) ^ (row & 7);
            gload16(A + (size_t)(bm + row) * K + kt + kc * 8, LA + (wave * 4 + c) * 512);
            gload16(Bt + (size_t)(bn + row) * K + kt + kc * 8, LB + (wave * 4 + c) * 512);
        }
        __syncthreads();
#pragma unroll
        for (int kk = 0; kk < 2; ++kk) {
            const int chunk = kk * 4 + (lane >> 4);
            bf16x8 a[4], b[4];
#pragma unroll
            for (int m = 0; m < 4; ++m) {
                int row = wr + m * 16 + fr;
                a[m] = *reinterpret_cast<const bf16x8*>(LA + row * 64 + ((chunk ^ (row & 7)) << 3));
            }
#pragma unroll
            for (int n = 0; n < 4; ++n) {
                int row = wc + n * 16 + fr;
                b[n] = *reinterpret_cast<const bf16x8*>(LB + row * 64 + ((chunk ^ (row & 7)) << 3));
            }
#pragma unroll
            for (int m = 0; m < 4; ++m)
#pragma unroll
                for (int n = 0; n < 4; ++n)
                    acc[m][n] = __builtin_amdgcn_mfma_f32_16x16x32_bf16(a[m], b[n], acc[m][n], 0, 0, 0);
        }
        __syncthreads();
    }
#pragma unroll
    for (int m = 0; m < 4; ++m)
#pragma unroll
        for (int j = 0; j < 4; ++j) {
            int grow = bm + wr + m * 16 + (lane >> 4) * 4 + j;
            float* cr = C + (size_t)grow * N + bn + wc + fr;
#pragma unroll
            for (int n = 0; n < 4; ++n) cr[n * 16] = acc[m][n][j];
        }
}

// ---------------- softmax rows (2048 cols) + optional bf16 copy -------------
__global__ __launch_bounds__(256)
void softmax_rows(float* __restrict__ P, unsigned short* __restrict__ albf)
{
    __shared__ float redm[4], reds[4];
    float* p = P + (size_t)blockIdx.x * 2048;
    const int tid = threadIdx.x, lane = tid & 63, wave = tid >> 6;

    f32x4 v0 = *reinterpret_cast<const f32x4*>(p + tid * 4);
    f32x4 v1 = *reinterpret_cast<const f32x4*>(p + 1024 + tid * 4);

    float mx = fmaxf(fmaxf(fmaxf(v0[0], v0[1]), fmaxf(v0[2], v0[3])),
                     fmaxf(fmaxf(v1[0], v1[1]), fmaxf(v1[2], v1[3])));
#pragma unroll
    for (int o = 32; o; o >>= 1) mx = fmaxf(mx, __shfl_xor(mx, o));
    if (lane == 0) redm[wave] = mx;
    __syncthreads();
    mx = fmaxf(fmaxf(redm[0], redm[1]), fmaxf(redm[2], redm[3]));

    float s = 0.f;
#pragma unroll
    for (int j = 0; j < 4; ++j) { v0[j] = __expf(v0[j] - mx); s += v0[j]; }
#pragma unroll
    for (int j = 0; j < 4; ++j) { v1[j] = __expf(v1[j] - mx); s += v1[j]; }
#pragma unroll
    for (int o = 32; o; o >>= 1) s += __shfl_xor(s, o);
    if (lane == 0) reds[wave] = s;
    __syncthreads();
    s = reds[0] + reds[1] + reds[2] + reds[3];

    const float inv = 1.0f / s;
#pragma unroll
    for (int j = 0; j < 4; ++j) { v0[j] *= inv; v1[j] *= inv; }
    *reinterpret_cast<f32x4*>(p + tid * 4) = v0;
    *reinterpret_cast<f32x4*>(p + 1024 + tid * 4) = v1;

    if (albf) {
        unsigned short* ab = albf + (size_t)blockIdx.x * 2048;
        u16x4 h0, h1;
#pragma unroll
        for (int j = 0; j < 4; ++j) { h0[j] = f2bf(v0[j]); h1[j] = f2bf(v1[j]); }
        *reinterpret_cast<u16x4*>(ab + tid * 4) = h0;
        *reinterpret_cast<u16x4*>(ab + 1024 + tid * 4) = h1;
    }
}

// ======================= round-1 fallback kernels ===========================
__device__ inline int tile_byte(int row, int kElem) {
    int chunk = kElem >> 3;
    return row * 128 + ((chunk ^ (row & 7)) << 4) + ((kElem & 7) << 1);
}

__global__ __launch_bounds__(256, 2)
void gemm_bt_x3(const float* __restrict__ A, long long sA,
                const float* __restrict__ Bt, long long sB,
                float* __restrict__ C, long long sC,
                int M, int N, int K)
{
    __shared__ unsigned short Ah[128 * 64], Al[128 * 64];
    __shared__ unsigned short Bh[128 * 64], Bl[128 * 64];

    const int tid = threadIdx.x, lane = tid & 63, wave = tid >> 6;
    const int wr = (wave >> 1) * 64, wc = (wave & 1) * 64;
    const int bm = blockIdx.y * 128, bn = blockIdx.x * 128;
    A += (size_t)blockIdx.z * sA;
    Bt += (size_t)blockIdx.z * sB;
    C += (size_t)blockIdx.z * sC;

    f32x4 acc[4][4] = {};

    for (int kt = 0; kt < K; kt += 64) {
#pragma unroll
        for (int i = 0; i < 8; ++i) {
            int idx = tid + i * 256;
            int row = idx >> 4, f4 = idx & 15;
            f32x4 va = *reinterpret_cast<const f32x4*>(A + (size_t)(bm + row) * K + kt + f4 * 4);
            f32x4 vb = *reinterpret_cast<const f32x4*>(Bt + (size_t)(bn + row) * K + kt + f4 * 4);
            u16x4 ah, al, bh, bl;
#pragma unroll
            for (int j = 0; j < 4; ++j) {
                unsigned short h = f2bf(va[j]);
                ah[j] = h; al[j] = f2bf(va[j] - bf2f(h));
                h = f2bf(vb[j]);
                bh[j] = h; bl[j] = f2bf(vb[j] - bf2f(h));
            }
            int off = tile_byte(row, f4 * 4);
            *reinterpret_cast<u16x4*>((char*)Ah + off) = ah;
            *reinterpret_cast<u16x4*>((char*)Al + off) = al;
            *reinterpret_cast<u16x4*>((char*)Bh + off) = bh;
            *reinterpret_cast<u16x4*>((char*)Bl + off) = bl;
        }
        __syncthreads();
#pragma unroll
        for (int kk = 0; kk < 2; ++kk) {
            bf16x8 a_h[4], a_l[4], b_h[4], b_l[4];
            const int kbase = kk * 32 + (lane >> 4) * 8;
#pragma unroll
            for (int m = 0; m < 4; ++m) {
                int off = tile_byte(wr + m * 16 + (lane & 15), kbase);
                a_h[m] = *reinterpret_cast<const bf16x8*>((char*)Ah + off);
                a_l[m] = *reinterpret_cast<const bf16x8*>((char*)Al + off);
            }
#pragma unroll
            for (int n = 0; n < 4; ++n) {
                int off = tile_byte(wc + n * 16 + (lane & 15), kbase);
                b_h[n] = *reinterpret_cast<const bf16x8*>((char*)Bh + off);
                b_l[n] = *reinterpret_cast<const bf16x8*>((char*)Bl + off);
            }
#pragma unroll
            for (int m = 0; m < 4; ++m)
#pragma unroll
                for (int n = 0; n < 4; ++n) {
                    acc[m][n] = __builtin_amdgcn_mfma_f32_16x16x32_bf16(a_h[m], b_h[n], acc[m][n], 0, 0, 0);
                    acc[m][n] = __builtin_amdgcn_mfma_f32_16x16x32_bf16(a_h[m], b_l[n], acc[m][n], 0, 0, 0);
                    acc[m][n] = __builtin_amdgcn_mfma_f32_16x16x32_bf16(a_l[m], b_h[n], acc[m][n], 0, 0, 0);
                }
        }
        __syncthreads();
    }
#pragma unroll
    for (int m = 0; m < 4; ++m)
#pragma unroll
        for (int j = 0; j < 4; ++j) {
            int grow = bm + wr + m * 16 + (lane >> 4) * 4 + j;
            float* cr = C + (size_t)grow * N + bn + wc + (lane & 15);
#pragma unroll
            for (int n = 0; n < 4; ++n) cr[n * 16] = acc[m][n][j];
        }
}

__global__ __launch_bounds__(256, 2)
void gemm_nn_bf16(const float* __restrict__ A, long long sA,
                  const float* __restrict__ Bn, long long sB,
                  float* __restrict__ C, long long sC,
                  int M, int N, int K)
{
    __shared__ unsigned short As[128 * 64];
    __shared__ unsigned short Bs[64 * 130];

    const int tid = threadIdx.x, lane = tid & 63, wave = tid >> 6;
    const int wr = (wave >> 1) * 64, wc = (wave & 1) * 64;
    const int bm = blockIdx.y * 128, bn = blockIdx.x * 128;
    A += (size_t)blockIdx.z * sA;
    Bn += (size_t)blockIdx.z * sB;
    C += (size_t)blockIdx.z * sC;

    f32x4 acc[4][4] = {};

    for (int kt = 0; kt < K; kt += 64) {
#pragma unroll
        for (int i = 0; i < 8; ++i) {
            int idx = tid + i * 256;
            int row = idx >> 4, f4 = idx & 15;
            f32x4 va = *reinterpret_cast<const f32x4*>(A + (size_t)(bm + row) * K + kt + f4 * 4);
            u16x4 h;
#pragma unroll
            for (int j = 0; j < 4; ++j) h[j] = f2bf(va[j]);
            *reinterpret_cast<u16x4*>((char*)As + tile_byte(row, f4 * 4)) = h;
        }
#pragma unroll
        for (int i = 0; i < 8; ++i) {
            int idx = tid + i * 256;
            int krow = idx >> 5, f4 = idx & 31;
            f32x4 vb = *reinterpret_cast<const f32x4*>(Bn + (size_t)(kt + krow) * N + bn + f4 * 4);
            unsigned int p0 = (unsigned int)f2bf(vb[0]) | ((unsigned int)f2bf(vb[1]) << 16);
            unsigned int p1 = (unsigned int)f2bf(vb[2]) | ((unsigned int)f2bf(vb[3]) << 16);
            unsigned int* bp = reinterpret_cast<unsigned int*>(&Bs[krow * 130 + f4 * 4]);
            bp[0] = p0; bp[1] = p1;
        }
        __syncthreads();
#pragma unroll
        for (int kk = 0; kk < 2; ++kk) {
            bf16x8 a[4], b[4];
            const int kbase = kk * 32 + (lane >> 4) * 8;
#pragma unroll
            for (int m = 0; m < 4; ++m)
                a[m] = *reinterpret_cast<const bf16x8*>((char*)As + tile_byte(wr + m * 16 + (lane & 15), kbase));
#pragma unroll
            for (int n = 0; n < 4; ++n) {
                int col = wc + n * 16 + (lane & 15);
                union { unsigned short u[8]; bf16x8 v; } t;
#pragma unroll
                for (int j = 0; j < 8; ++j) t.u[j] = Bs[(kbase + j) * 130 + col];
                b[n] = t.v;
            }
#pragma unroll
            for (int m = 0; m < 4; ++m)
#pragma unroll
                for (int n = 0; n < 4; ++n)
                    acc[m][n] = __builtin_amdgcn_mfma_f32_16x16x32_bf16(a[m], b[n], acc[m][n], 0, 0, 0);
        }
        __syncthreads();
    }
#pragma unroll
    for (int m = 0; m < 4; ++m)
#pragma unroll
        for (int j = 0; j < 4; ++j) {
            int grow = bm + wr + m * 16 + (lane >> 4) * 4 + j;
            float* cr = C + (size_t)grow * N + bn + wc + (lane & 15);
#pragma unroll
            for (int n = 0; n < 4; ++n) cr[n * 16] = acc[m][n][j];
        }
}

// ============================================================================
extern "C" void kernel_launch(void* const* d_in, const int* in_sizes, int n_in,
                              void* d_out, int out_size, void* d_ws, size_t ws_size,
                              hipStream_t stream)
{
    (void)in_sizes; (void)n_in; (void)out_size;
    const float* dec = (const float*)d_in[0];   // [16,512,1024]
    const float* enc = (const float*)d_in[1];   // [16,2048,1024]
    const float* W   = (const float*)d_in[2];   // [1024,1024]

    float* ctx   = (float*)d_out;                            // [16,512,1024]
    float* align = (float*)d_out + (size_t)16 * 512 * 1024;  // [16,512,2048]

    const size_t NEED_FAST = (size_t)(33554432ULL * 2 + 16777216ULL) * 2;  // 160 MiB

    if (ws_size >= NEED_FAST) {
        // scratch aliases
        unsigned short* enc_h   = (unsigned short*)d_ws;             // 64 MiB
        unsigned short* enc_l   = enc_h + 33554432ULL;               // 64 MiB
        unsigned short* align_b = enc_l + 33554432ULL;               // 32 MiB
        unsigned short* encT    = enc_l;                             // reuses enc_l after K2
        unsigned short* dproj_h = (unsigned short*)d_out;            // ctx region (dead)
        unsigned short* dproj_l = dproj_h + 8388608ULL;
        unsigned short* dec_h   = (unsigned short*)align;            // align region (dead)
        unsigned short* dec_l   = dec_h + 8388608ULL;
        unsigned short* W_h     = dec_l + 8388608ULL;
        unsigned short* W_l     = W_h + 1048576ULL;

        // P0: splits
        split_bf16<<<16384, 256, 0, stream>>>(enc, enc_h, enc_l, 4194304);
        split_bf16<<<4096, 256, 0, stream>>>(dec, dec_h, dec_l, 1048576);
        split_bf16<<<512, 256, 0, stream>>>(W, W_h, W_l, 131072);

        // K1: dproj = dec @ W^T  (M=8192, N=1024, K=1024) -> bf16 split planes
        gemm_bt3_bf16<1><<<dim3(8, 64, 1), 256, 0, stream>>>(
            dec_h, dec_l, 0, W_h, W_l, 0,
            nullptr, dproj_h, dproj_l, 0, 8192, 1024, 1024);

        // K2: score = dproj @ enc^T per batch (M=512, N=2048, K=1024) -> align
        gemm_bt3_bf16<0><<<dim3(16, 4, 16), 256, 0, stream>>>(
            dproj_h, dproj_l, 512LL * 1024, enc_h, enc_l, 2048LL * 1024,
            align, nullptr, nullptr, 512LL * 2048, 512, 2048, 1024);

        // T: encT[b][d][k] = enc_h[b][k][d]   (enc_l region is dead now)
        transpose_bf16<<<dim3(32, 16, 16), 256, 0, stream>>>(enc_h, encT);

        // K3: softmax + bf16 copy
        softmax_rows<<<8192, 256, 0, stream>>>(align, align_b);

        // K4: ctx = align_b @ encT^T per batch (M=512, N=1024, K=2048)
        gemm_bt_bf16<<<dim3(8, 4, 16), 256, 0, stream>>>(
            align_b, 512LL * 2048, encT, 1024LL * 2048, ctx, 512LL * 1024,
            512, 1024, 2048);
    } else {
        // round-1 fallback (needs 32 MiB ws)
        float* dproj = (float*)d_ws;
        gemm_bt_x3<<<dim3(8, 64, 1), 256, 0, stream>>>(
            dec, 0, W, 0, dproj, 0, 8192, 1024, 1024);
        gemm_bt_x3<<<dim3(16, 4, 16), 256, 0, stream>>>(
            dproj, 512LL * 1024, enc, 2048LL * 1024, align, 512LL * 2048, 512, 2048, 1024);
        softmax_rows<<<8192, 256, 0, stream>>>(align, nullptr);
        gemm_nn_bf16<<<dim3(8, 4, 16), 256, 0, stream>>>(
            align, 512LL * 2048, enc, 2048LL * 1024, ctx, 512LL * 1024, 512, 1024, 2048);
    }
}

// Round 4
// 308.606 us; speedup vs baseline: 1.8194x; 1.1007x over previous
//
#include <hip/hip_runtime.h>
#include <hip/hip_bf16.h>

// LuongAttention: B=16, Tq=512, Tk=2048, D=1024 (fp32 in/out)
// Fast path (needs ws >= 160 MiB):
//   P0: split enc/dec/W into bf16 hi/lo planes (elementwise, memory-bound)
//   K1: dproj_h/l = split(dec @ W^T)        pure-bf16 x3 BT GEMM (global_load_lds)
//   K2: score = dproj @ enc^T -> align area NEW: 256x256 8-wave dbuf x3 GEMM
//   T:  encT = transpose(enc_h)             bf16 LDS tile transpose
//   K3: softmax in place + bf16 copy (align_b)
//   K4: ctx = align_b @ encT^T              pure-bf16 x1 BT GEMM (global_load_lds)
// wa_bias cancels in softmax -> skipped.

typedef float f32x4 __attribute__((ext_vector_type(4)));
typedef __bf16 bf16x8 __attribute__((ext_vector_type(8)));
typedef unsigned short u16x4 __attribute__((ext_vector_type(4)));
typedef unsigned short u16x8 __attribute__((ext_vector_type(8)));

__device__ inline unsigned short f2bf(float f) {
    union { float f; unsigned int u; } v; v.f = f;
    unsigned int r = v.u + 0x7fffu + ((v.u >> 16) & 1u);  // RN-even
    return (unsigned short)(r >> 16);
}
__device__ inline float bf2f(unsigned short h) {
    union { unsigned int u; float f; } v; v.u = ((unsigned int)h) << 16; return v.f;
}

__device__ inline void gload16(const void* g, const void* l) {
    __builtin_amdgcn_global_load_lds(
        (const __attribute__((address_space(1))) unsigned int*)g,
        (__attribute__((address_space(3))) unsigned int*)l, 16, 0, 0);
}

// ---------------- P0: fp32 -> bf16 hi/lo split (elementwise) ----------------
__global__ __launch_bounds__(256)
void split_bf16(const float* __restrict__ x, unsigned short* __restrict__ ho,
                unsigned short* __restrict__ lo, int n8)
{
    int i = blockIdx.x * 256 + threadIdx.x;
    if (i >= n8) return;
    const f32x4* xp = reinterpret_cast<const f32x4*>(x + (size_t)i * 8);
    f32x4 v0 = xp[0], v1 = xp[1];
    u16x8 h, l;
#pragma unroll
    for (int j = 0; j < 4; ++j) {
        unsigned short hh = f2bf(v0[j]);
        h[j] = hh; l[j] = f2bf(v0[j] - bf2f(hh));
        hh = f2bf(v1[j]);
        h[4 + j] = hh; l[4 + j] = f2bf(v1[j] - bf2f(hh));
    }
    *reinterpret_cast<u16x8*>(ho + (size_t)i * 8) = h;
    *reinterpret_cast<u16x8*>(lo + (size_t)i * 8) = l;
}

// ------- T: bf16 transpose  in [16][2048][1024] -> out [16][1024][2048] -----
__global__ __launch_bounds__(256)
void transpose_bf16(const unsigned short* __restrict__ in, unsigned short* __restrict__ out)
{
    __shared__ unsigned short t[64][65];
    const int b = blockIdx.z;
    const int kb = blockIdx.x * 64;
    const int db = blockIdx.y * 64;
    const unsigned short* ip = in + ((size_t)b * 2048 + kb) * 1024 + db;
    unsigned short* op = out + ((size_t)b * 1024 + db) * 2048 + kb;
    const int r = threadIdx.x >> 3;
    const int c0 = (threadIdx.x & 7) * 8;
#pragma unroll
    for (int h = 0; h < 2; ++h) {
        u16x8 v = *reinterpret_cast<const u16x8*>(ip + (size_t)(r + h * 32) * 1024 + c0);
#pragma unroll
        for (int j = 0; j < 8; ++j) t[c0 + j][r + h * 32] = v[j];
    }
    __syncthreads();
#pragma unroll
    for (int h = 0; h < 2; ++h) {
        int orow = r + h * 32;
        u16x8 v = *reinterpret_cast<const u16x8*>(&t[orow][c0]);
        *reinterpret_cast<u16x8*>(op + (size_t)orow * 2048 + c0) = v;
    }
}

// ========== K2: 256x256 8-wave double-buffered x3 BT GEMM ===================
// C = (Ah+Al) @ (Bh+Bl)^T, A [M,K], B [N,K] bf16, M,N % 256 == 0, K % 32 == 0.
// BK=32; LDS rows 64B; physical slot = (kc + (row>>1)) & 3 -> 8 consecutive
// rows cover all 8 bank-groups (conflict-floor). Linear LDS dest (gload_lds),
// pre-swizzled global source. 2-phase pipeline: stage(next) issued before
// compute(cur); single __syncthreads per K-step drains vmcnt after MFMA.
// Grid: 1D, nwg = (M/256)*(N/256)*batch, XCD-swizzled, batch-major decode.
__global__ __launch_bounds__(512, 2)
void gemm_bt3_wide(const unsigned short* __restrict__ Ah, const unsigned short* __restrict__ Al,
                   long long sA,
                   const unsigned short* __restrict__ Bh, const unsigned short* __restrict__ Bl,
                   long long sB,
                   float* __restrict__ C, long long sC,
                   int M, int N, int K)
{
    __shared__ unsigned short smem[2 * 4 * 8192];   // 128 KiB: [buf][Ah,Al,Bh,Bl][256*32]

    const int tid = threadIdx.x, lane = tid & 63, wave = tid >> 6;

    // XCD swizzle (nwg % 8 == 0) + batch-major decode
    const int nwg = gridDim.x;
    int orig = (blockIdx.x & 7) * (nwg >> 3) + (blockIdx.x >> 3);
    const int mb = M >> 8, nb = N >> 8, bpb = mb * nb;
    const int z = orig / bpb, rem = orig - z * bpb;
    const int bm = (rem % mb) << 8, bn = (rem / mb) << 8;

    Ah += (size_t)z * sA; Al += (size_t)z * sA;
    Bh += (size_t)z * sB; Bl += (size_t)z * sB;
    C  += (size_t)z * sC;

    // staging geometry: per array 1024 slots of 16B (256 rows x 4 chunks);
    // 512 threads x 2 calls. LDS slot s holds global chunk g=(s-(row>>1))&3.
    const int idx0 = wave * 128 + lane, idx1 = idx0 + 64;
    const int r0 = idx0 >> 2, s0 = idx0 & 3, g0 = (s0 + 4 - ((r0 >> 1) & 3)) & 3;
    const int r1 = idx1 >> 2, s1 = idx1 & 3, g1 = (s1 + 4 - ((r1 >> 1) & 3)) & 3;
    const size_t aoff0 = (size_t)(bm + r0) * K + g0 * 8;
    const size_t aoff1 = (size_t)(bm + r1) * K + g1 * 8;
    const size_t boff0 = (size_t)(bn + r0) * K + g0 * 8;
    const size_t boff1 = (size_t)(bn + r1) * K + g1 * 8;
    const int d0 = wave * 1024, d1 = d0 + 512;   // u16 elems, wave-uniform base

    const int kcL = lane >> 4, fr = lane & 15;
    const int wrow = (wave >> 2) * 128;   // 2 wave-rows x 128
    const int wcol = (wave & 3) * 64;     // 4 wave-cols x 64

    f32x4 acc[8][4] = {};
    const int nt = K >> 5;
    int cur = 0;

    {   // prologue: stage K-tile 0 into buf 0
        unsigned short* b = smem;
        gload16(Ah + aoff0, b + d0);           gload16(Ah + aoff1, b + d1);
        gload16(Al + aoff0, b + 8192 + d0);    gload16(Al + aoff1, b + 8192 + d1);
        gload16(Bh + boff0, b + 16384 + d0);   gload16(Bh + boff1, b + 16384 + d1);
        gload16(Bl + boff0, b + 24576 + d0);   gload16(Bl + boff1, b + 24576 + d1);
    }
    __syncthreads();

    for (int t = 0; t < nt; ++t) {
        if (t + 1 < nt) {   // issue next-tile stage BEFORE compute (2-phase)
            const int kt = (t + 1) << 5;
            unsigned short* b = smem + (cur ^ 1) * 32768;
            gload16(Ah + aoff0 + kt, b + d0);           gload16(Ah + aoff1 + kt, b + d1);
            gload16(Al + aoff0 + kt, b + 8192 + d0);    gload16(Al + aoff1 + kt, b + 8192 + d1);
            gload16(Bh + boff0 + kt, b + 16384 + d0);   gload16(Bh + boff1 + kt, b + 16384 + d1);
            gload16(Bl + boff0 + kt, b + 24576 + d0);   gload16(Bl + boff1 + kt, b + 24576 + d1);
        }
        const unsigned short* base = smem + cur * 32768;
        bf16x8 bhf[4], blf[4];
#pragma unroll
        for (int n = 0; n < 4; ++n) {
            int row = wcol + n * 16 + fr;
            int off = row * 32 + (((kcL + (row >> 1)) & 3) << 3);
            bhf[n] = *reinterpret_cast<const bf16x8*>(base + 16384 + off);
            blf[n] = *reinterpret_cast<const bf16x8*>(base + 24576 + off);
        }
#pragma unroll
        for (int m = 0; m < 8; ++m) {
            int row = wrow + m * 16 + fr;
            int off = row * 32 + (((kcL + (row >> 1)) & 3) << 3);
            bf16x8 ah = *reinterpret_cast<const bf16x8*>(base + off);
            bf16x8 al = *reinterpret_cast<const bf16x8*>(base + 8192 + off);
#pragma unroll
            for (int n = 0; n < 4; ++n) {
                acc[m][n] = __builtin_amdgcn_mfma_f32_16x16x32_bf16(ah, bhf[n], acc[m][n], 0, 0, 0);
                acc[m][n] = __builtin_amdgcn_mfma_f32_16x16x32_bf16(ah, blf[n], acc[m][n], 0, 0, 0);
                acc[m][n] = __builtin_amdgcn_mfma_f32_16x16x32_bf16(al, bhf[n], acc[m][n], 0, 0, 0);
            }
        }
        __syncthreads();   // drains vmcnt(0): next buf staged; all reads of cur done
        cur ^= 1;
    }

    // C/D layout: col = lane&15, row = (lane>>4)*4 + j  [HW-verified]
#pragma unroll
    for (int m = 0; m < 8; ++m)
#pragma unroll
        for (int j = 0; j < 4; ++j) {
            int grow = bm + wrow + m * 16 + (lane >> 4) * 4 + j;
            float* cr = C + (size_t)grow * N + bn + wcol + fr;
#pragma unroll
            for (int n = 0; n < 4; ++n) cr[n * 16] = acc[m][n][j];
        }
}

// ------------- K1: 128x128 4-wave x3 BT GEMM (round-3, proven) --------------
// OUTMODE 0: fp32 C.  OUTMODE 1: bf16 hi/lo split -> Ch, Cl.
template<int OUTMODE>
__global__ __launch_bounds__(256, 3)
void gemm_bt3_bf16(const unsigned short* __restrict__ Ah, const unsigned short* __restrict__ Al,
                   long long sA,
                   const unsigned short* __restrict__ Bh, const unsigned short* __restrict__ Bl,
                   long long sB,
                   float* __restrict__ C, unsigned short* __restrict__ Ch,
                   unsigned short* __restrict__ Cl, long long sC,
                   int M, int N, int K)
{
    __shared__ unsigned short LAh[128 * 32], LAl[128 * 32];
    __shared__ unsigned short LBh[128 * 32], LBl[128 * 32];

    const int tid = threadIdx.x, lane = tid & 63, wave = tid >> 6;
    const int wr = (wave >> 1) * 64, wc = (wave & 1) * 64;
    const int bm = blockIdx.y * 128, bn = blockIdx.x * 128;
    Ah += (size_t)blockIdx.z * sA; Al += (size_t)blockIdx.z * sA;
    Bh += (size_t)blockIdx.z * sB; Bl += (size_t)blockIdx.z * sB;

    f32x4 acc[4][4] = {};

    int cid0 = wave * 128 + lane;
    int cid1 = wave * 128 + 64 + lane;
    int r0 = cid0 >> 2, kc0 = (cid0 & 3) ^ ((r0 >> 2) & 3);
    int r1 = cid1 >> 2, kc1 = (cid1 & 3) ^ ((r1 >> 2) & 3);
    int lb0 = (wave * 2 + 0) * 512;
    int lb1 = (wave * 2 + 1) * 512;

    const int kcL = lane >> 4;
    const int fr = lane & 15;

    for (int kt = 0; kt < K; kt += 32) {
        gload16(Ah + (size_t)(bm + r0) * K + kt + kc0 * 8, LAh + lb0);
        gload16(Ah + (size_t)(bm + r1) * K + kt + kc1 * 8, LAh + lb1);
        gload16(Al + (size_t)(bm + r0) * K + kt + kc0 * 8, LAl + lb0);
        gload16(Al + (size_t)(bm + r1) * K + kt + kc1 * 8, LAl + lb1);
        gload16(Bh + (size_t)(bn + r0) * K + kt + kc0 * 8, LBh + lb0);
        gload16(Bh + (size_t)(bn + r1) * K + kt + kc1 * 8, LBh + lb1);
        gload16(Bl + (size_t)(bn + r0) * K + kt + kc0 * 8, LBl + lb0);
        gload16(Bl + (size_t)(bn + r1) * K + kt + kc1 * 8, LBl + lb1);
        __syncthreads();

        bf16x8 bh[4], bl[4];
#pragma unroll
        for (int n = 0; n < 4; ++n) {
            int row = wc + n * 16 + fr;
            int off = row * 32 + ((kcL ^ ((row >> 2) & 3)) << 3);
            bh[n] = *reinterpret_cast<const bf16x8*>(LBh + off);
            bl[n] = *reinterpret_cast<const bf16x8*>(LBl + off);
        }
#pragma unroll
        for (int m = 0; m < 4; ++m) {
            int row = wr + m * 16 + fr;
            int off = row * 32 + ((kcL ^ ((row >> 2) & 3)) << 3);
            bf16x8 ah = *reinterpret_cast<const bf16x8*>(LAh + off);
            bf16x8 al = *reinterpret_cast<const bf16x8*>(LAl + off);
#pragma unroll
            for (int n = 0; n < 4; ++n) {
                acc[m][n] = __builtin_amdgcn_mfma_f32_16x16x32_bf16(ah, bh[n], acc[m][n], 0, 0, 0);
                acc[m][n] = __builtin_amdgcn_mfma_f32_16x16x32_bf16(ah, bl[n], acc[m][n], 0, 0, 0);
                acc[m][n] = __builtin_amdgcn_mfma_f32_16x16x32_bf16(al, bh[n], acc[m][n], 0, 0, 0);
            }
        }
        __syncthreads();
    }

    if (OUTMODE == 0) {
        C += (size_t)blockIdx.z * sC;
#pragma unroll
        for (int m = 0; m < 4; ++m)
#pragma unroll
            for (int j = 0; j < 4; ++j) {
                int grow = bm + wr + m * 16 + (lane >> 4) * 4 + j;
                float* cr = C + (size_t)grow * N + bn + wc + fr;
#pragma unroll
                for (int n = 0; n < 4; ++n) cr[n * 16] = acc[m][n][j];
            }
    } else {
        Ch += (size_t)blockIdx.z * sC; Cl += (size_t)blockIdx.z * sC;
#pragma unroll
        for (int m = 0; m < 4; ++m)
#pragma unroll
            for (int j = 0; j < 4; ++j) {
                int grow = bm + wr + m * 16 + (lane >> 4) * 4 + j;
                size_t rb = (size_t)grow * N + bn + wc + fr;
#pragma unroll
                for (int n = 0; n < 4; ++n) {
                    float v = acc[m][n][j];
                    unsigned short hh = f2bf(v);
                    Ch[rb + n * 16] = hh;
                    Cl[rb + n * 16] = f2bf(v - bf2f(hh));
                }
            }
    }
}

// ---------- K4: pure-bf16 x1 BT GEMM: C = A @ Bt^T, BK=64 -------------------
__global__ __launch_bounds__(256, 3)
void gemm_bt_bf16(const unsigned short* __restrict__ A, long long sA,
                  const unsigned short* __restrict__ Bt, long long sB,
                  float* __restrict__ C, long long sC,
                  int M, int N, int K)
{
    __shared__ unsigned short LA[128 * 64], LB[128 * 64];

    const int tid = threadIdx.x, lane = tid & 63, wave = tid >> 6;
    const int wr = (wave >> 1) * 64, wc = (wave & 1) * 64;
    const int bm = blockIdx.y * 128, bn = blockIdx.x * 128;
    A += (size_t)blockIdx.z * sA;
    Bt += (size_t)blockIdx.z * sB;
    C += (size_t)blockIdx.z * sC;

    f32x4 acc[4][4] = {};
    const int fr = lane & 15;

    for (int kt = 0; kt < K; kt += 64) {
#pragma unroll
        for (int c = 0; c < 4; ++c) {
            int cid = (wave * 4 + c) * 64 + lane;
            int row = cid >> 3;
            int kc = (cid & 7) ^ (row & 7);
            gload16(A + (size_t)(bm + row) * K + kt + kc * 8, LA + (wave * 4 + c) * 512);
            gload16(Bt + (size_t)(bn + row) * K + kt + kc * 8, LB + (wave * 4 + c) * 512);
        }
        __syncthreads();
#pragma unroll
        for (int kk = 0; kk < 2; ++kk) {
            const int chunk = kk * 4 + (lane >> 4);
            bf16x8 a[4], b[4];
#pragma unroll
            for (int m = 0; m < 4; ++m) {
                int row = wr + m * 16 + fr;
                a[m] = *reinterpret_cast<const bf16x8*>(LA + row * 64 + ((chunk ^ (row & 7)) << 3));
            }
#pragma unroll
            for (int n = 0; n < 4; ++n) {
                int row = wc + n * 16 + fr;
                b[n] = *reinterpret_cast<const bf16x8*>(LB + row * 64 + ((chunk ^ (row & 7)) << 3));
            }
#pragma unroll
            for (int m = 0; m < 4; ++m)
#pragma unroll
                for (int n = 0; n < 4; ++n)
                    acc[m][n] = __builtin_amdgcn_mfma_f32_16x16x32_bf16(a[m], b[n], acc[m][n], 0, 0, 0);
        }
        __syncthreads();
    }
#pragma unroll
    for (int m = 0; m < 4; ++m)
#pragma unroll
        for (int j = 0; j < 4; ++j) {
            int grow = bm + wr + m * 16 + (lane >> 4) * 4 + j;
            float* cr = C + (size_t)grow * N + bn + wc + fr;
#pragma unroll
            for (int n = 0; n < 4; ++n) cr[n * 16] = acc[m][n][j];
        }
}

// ---------------- softmax rows (2048 cols) + optional bf16 copy -------------
__global__ __launch_bounds__(256)
void softmax_rows(float* __restrict__ P, unsigned short* __restrict__ albf)
{
    __shared__ float redm[4], reds[4];
    float* p = P + (size_t)blockIdx.x * 2048;
    const int tid = threadIdx.x, lane = tid & 63, wave = tid >> 6;

    f32x4 v0 = *reinterpret_cast<const f32x4*>(p + tid * 4);
    f32x4 v1 = *reinterpret_cast<const f32x4*>(p + 1024 + tid * 4);

    float mx = fmaxf(fmaxf(fmaxf(v0[0], v0[1]), fmaxf(v0[2], v0[3])),
                     fmaxf(fmaxf(v1[0], v1[1]), fmaxf(v1[2], v1[3])));
#pragma unroll
    for (int o = 32; o; o >>= 1) mx = fmaxf(mx, __shfl_xor(mx, o));
    if (lane == 0) redm[wave] = mx;
    __syncthreads();
    mx = fmaxf(fmaxf(redm[0], redm[1]), fmaxf(redm[2], redm[3]));

    float s = 0.f;
#pragma unroll
    for (int j = 0; j < 4; ++j) { v0[j] = __expf(v0[j] - mx); s += v0[j]; }
#pragma unroll
    for (int j = 0; j < 4; ++j) { v1[j] = __expf(v1[j] - mx); s += v1[j]; }
#pragma unroll
    for (int o = 32; o; o >>= 1) s += __shfl_xor(s, o);
    if (lane == 0) reds[wave] = s;
    __syncthreads();
    s = reds[0] + reds[1] + reds[2] + reds[3];

    const float inv = 1.0f / s;
#pragma unroll
    for (int j = 0; j < 4; ++j) { v0[j] *= inv; v1[j] *= inv; }
    *reinterpret_cast<f32x4*>(p + tid * 4) = v0;
    *reinterpret_cast<f32x4*>(p + 1024 + tid * 4) = v1;

    if (albf) {
        unsigned short* ab = albf + (size_t)blockIdx.x * 2048;
        u16x4 h0, h1;
#pragma unroll
        for (int j = 0; j < 4; ++j) { h0[j] = f2bf(v0[j]); h1[j] = f2bf(v1[j]); }
        *reinterpret_cast<u16x4*>(ab + tid * 4) = h0;
        *reinterpret_cast<u16x4*>(ab + 1024 + tid * 4) = h1;
    }
}

// ======================= round-1 fallback kernels ===========================
__device__ inline int tile_byte(int row, int kElem) {
    int chunk = kElem >> 3;
    return row * 128 + ((chunk ^ (row & 7)) << 4) + ((kElem & 7) << 1);
}

__global__ __launch_bounds__(256, 2)
void gemm_bt_x3(const float* __restrict__ A, long long sA,
                const float* __restrict__ Bt, long long sB,
                float* __restrict__ C, long long sC,
                int M, int N, int K)
{
    __shared__ unsigned short Ah[128 * 64], Al[128 * 64];
    __shared__ unsigned short Bh[128 * 64], Bl[128 * 64];

    const int tid = threadIdx.x, lane = tid & 63, wave = tid >> 6;
    const int wr = (wave >> 1) * 64, wc = (wave & 1) * 64;
    const int bm = blockIdx.y * 128, bn = blockIdx.x * 128;
    A += (size_t)blockIdx.z * sA;
    Bt += (size_t)blockIdx.z * sB;
    C += (size_t)blockIdx.z * sC;

    f32x4 acc[4][4] = {};

    for (int kt = 0; kt < K; kt += 64) {
#pragma unroll
        for (int i = 0; i < 8; ++i) {
            int idx = tid + i * 256;
            int row = idx >> 4, f4 = idx & 15;
            f32x4 va = *reinterpret_cast<const f32x4*>(A + (size_t)(bm + row) * K + kt + f4 * 4);
            f32x4 vb = *reinterpret_cast<const f32x4*>(Bt + (size_t)(bn + row) * K + kt + f4 * 4);
            u16x4 ah, al, bh, bl;
#pragma unroll
            for (int j = 0; j < 4; ++j) {
                unsigned short h = f2bf(va[j]);
                ah[j] = h; al[j] = f2bf(va[j] - bf2f(h));
                h = f2bf(vb[j]);
                bh[j] = h; bl[j] = f2bf(vb[j] - bf2f(h));
            }
            int off = tile_byte(row, f4 * 4);
            *reinterpret_cast<u16x4*>((char*)Ah + off) = ah;
            *reinterpret_cast<u16x4*>((char*)Al + off) = al;
            *reinterpret_cast<u16x4*>((char*)Bh + off) = bh;
            *reinterpret_cast<u16x4*>((char*)Bl + off) = bl;
        }
        __syncthreads();
#pragma unroll
        for (int kk = 0; kk < 2; ++kk) {
            bf16x8 a_h[4], a_l[4], b_h[4], b_l[4];
            const int kbase = kk * 32 + (lane >> 4) * 8;
#pragma unroll
            for (int m = 0; m < 4; ++m) {
                int off = tile_byte(wr + m * 16 + (lane & 15), kbase);
                a_h[m] = *reinterpret_cast<const bf16x8*>((char*)Ah + off);
                a_l[m] = *reinterpret_cast<const bf16x8*>((char*)Al + off);
            }
#pragma unroll
            for (int n = 0; n < 4; ++n) {
                int off = tile_byte(wc + n * 16 + (lane & 15), kbase);
                b_h[n] = *reinterpret_cast<const bf16x8*>((char*)Bh + off);
                b_l[n] = *reinterpret_cast<const bf16x8*>((char*)Bl + off);
            }
#pragma unroll
            for (int m = 0; m < 4; ++m)
#pragma unroll
                for (int n = 0; n < 4; ++n) {
                    acc[m][n] = __builtin_amdgcn_mfma_f32_16x16x32_bf16(a_h[m], b_h[n], acc[m][n], 0, 0, 0);
                    acc[m][n] = __builtin_amdgcn_mfma_f32_16x16x32_bf16(a_h[m], b_l[n], acc[m][n], 0, 0, 0);
                    acc[m][n] = __builtin_amdgcn_mfma_f32_16x16x32_bf16(a_l[m], b_h[n], acc[m][n], 0, 0, 0);
                }
        }
        __syncthreads();
    }
#pragma unroll
    for (int m = 0; m < 4; ++m)
#pragma unroll
        for (int j = 0; j < 4; ++j) {
            int grow = bm + wr + m * 16 + (lane >> 4) * 4 + j;
            float* cr = C + (size_t)grow * N + bn + wc + (lane & 15);
#pragma unroll
            for (int n = 0; n < 4; ++n) cr[n * 16] = acc[m][n][j];
        }
}

__global__ __launch_bounds__(256, 2)
void gemm_nn_bf16(const float* __restrict__ A, long long sA,
                  const float* __restrict__ Bn, long long sB,
                  float* __restrict__ C, long long sC,
                  int M, int N, int K)
{
    __shared__ unsigned short As[128 * 64];
    __shared__ unsigned short Bs[64 * 130];

    const int tid = threadIdx.x, lane = tid & 63, wave = tid >> 6;
    const int wr = (wave >> 1) * 64, wc = (wave & 1) * 64;
    const int bm = blockIdx.y * 128, bn = blockIdx.x * 128;
    A += (size_t)blockIdx.z * sA;
    Bn += (size_t)blockIdx.z * sB;
    C += (size_t)blockIdx.z * sC;

    f32x4 acc[4][4] = {};

    for (int kt = 0; kt < K; kt += 64) {
#pragma unroll
        for (int i = 0; i < 8; ++i) {
            int idx = tid + i * 256;
            int row = idx >> 4, f4 = idx & 15;
            f32x4 va = *reinterpret_cast<const f32x4*>(A + (size_t)(bm + row) * K + kt + f4 * 4);
            u16x4 h;
#pragma unroll
            for (int j = 0; j < 4; ++j) h[j] = f2bf(va[j]);
            *reinterpret_cast<u16x4*>((char*)As + tile_byte(row, f4 * 4)) = h;
        }
#pragma unroll
        for (int i = 0; i < 8; ++i) {
            int idx = tid + i * 256;
            int krow = idx >> 5, f4 = idx & 31;
            f32x4 vb = *reinterpret_cast<const f32x4*>(Bn + (size_t)(kt + krow) * N + bn + f4 * 4);
            unsigned int p0 = (unsigned int)f2bf(vb[0]) | ((unsigned int)f2bf(vb[1]) << 16);
            unsigned int p1 = (unsigned int)f2bf(vb[2]) | ((unsigned int)f2bf(vb[3]) << 16);
            unsigned int* bp = reinterpret_cast<unsigned int*>(&Bs[krow * 130 + f4 * 4]);
            bp[0] = p0; bp[1] = p1;
        }
        __syncthreads();
#pragma unroll
        for (int kk = 0; kk < 2; ++kk) {
            bf16x8 a[4], b[4];
            const int kbase = kk * 32 + (lane >> 4) * 8;
#pragma unroll
            for (int m = 0; m < 4; ++m)
                a[m] = *reinterpret_cast<const bf16x8*>((char*)As + tile_byte(wr + m * 16 + (lane & 15), kbase));
#pragma unroll
            for (int n = 0; n < 4; ++n) {
                int col = wc + n * 16 + (lane & 15);
                union { unsigned short u[8]; bf16x8 v; } t;
#pragma unroll
                for (int j = 0; j < 8; ++j) t.u[j] = Bs[(kbase + j) * 130 + col];
                b[n] = t.v;
            }
#pragma unroll
            for (int m = 0; m < 4; ++m)
#pragma unroll
                for (int n = 0; n < 4; ++n)
                    acc[m][n] = __builtin_amdgcn_mfma_f32_16x16x32_bf16(a[m], b[n], acc[m][n], 0, 0, 0);
        }
        __syncthreads();
    }
#pragma unroll
    for (int m = 0; m < 4; ++m)
#pragma unroll
        for (int j = 0; j < 4; ++j) {
            int grow = bm + wr + m * 16 + (lane >> 4) * 4 + j;
            float* cr = C + (size_t)grow * N + bn + wc + (lane & 15);
#pragma unroll
            for (int n = 0; n < 4; ++n) cr[n * 16] = acc[m][n][j];
        }
}

// ============================================================================
extern "C" void kernel_launch(void* const* d_in, const int* in_sizes, int n_in,
                              void* d_out, int out_size, void* d_ws, size_t ws_size,
                              hipStream_t stream)
{
    (void)in_sizes; (void)n_in; (void)out_size;
    const float* dec = (const float*)d_in[0];   // [16,512,1024]
    const float* enc = (const float*)d_in[1];   // [16,2048,1024]
    const float* W   = (const float*)d_in[2];   // [1024,1024]

    float* ctx   = (float*)d_out;                            // [16,512,1024]
    float* align = (float*)d_out + (size_t)16 * 512 * 1024;  // [16,512,2048]

    const size_t NEED_FAST = (size_t)(33554432ULL * 2 + 16777216ULL) * 2;  // 160 MiB

    if (ws_size >= NEED_FAST) {
        unsigned short* enc_h   = (unsigned short*)d_ws;             // 64 MiB
        unsigned short* enc_l   = enc_h + 33554432ULL;               // 64 MiB
        unsigned short* align_b = enc_l + 33554432ULL;               // 32 MiB
        unsigned short* encT    = enc_l;                             // reuses enc_l after K2
        unsigned short* dproj_h = (unsigned short*)d_out;            // ctx region (dead)
        unsigned short* dproj_l = dproj_h + 8388608ULL;
        unsigned short* dec_h   = (unsigned short*)align;            // align region (dead)
        unsigned short* dec_l   = dec_h + 8388608ULL;
        unsigned short* W_h     = dec_l + 8388608ULL;
        unsigned short* W_l     = W_h + 1048576ULL;

        // P0: splits
        split_bf16<<<16384, 256, 0, stream>>>(enc, enc_h, enc_l, 4194304);
        split_bf16<<<4096, 256, 0, stream>>>(dec, dec_h, dec_l, 1048576);
        split_bf16<<<512, 256, 0, stream>>>(W, W_h, W_l, 131072);

        // K1: dproj = dec @ W^T  (M=8192, N=1024, K=1024) -> bf16 split planes
        gemm_bt3_bf16<1><<<dim3(8, 64, 1), 256, 0, stream>>>(
            dec_h, dec_l, 0, W_h, W_l, 0,
            nullptr, dproj_h, dproj_l, 0, 8192, 1024, 1024);

        // K2: score = dproj @ enc^T per batch (M=512, N=2048, K=1024) -> align
        // 256 blocks = 1/CU, 8 waves, 2-phase dbuf
        gemm_bt3_wide<<<256, 512, 0, stream>>>(
            dproj_h, dproj_l, 512LL * 1024, enc_h, enc_l, 2048LL * 1024,
            align, 512LL * 2048, 512, 2048, 1024);

        // T: encT[b][d][k] = enc_h[b][k][d]   (enc_l region is dead now)
        transpose_bf16<<<dim3(32, 16, 16), 256, 0, stream>>>(enc_h, encT);

        // K3: softmax + bf16 copy
        softmax_rows<<<8192, 256, 0, stream>>>(align, align_b);

        // K4: ctx = align_b @ encT^T per batch (M=512, N=1024, K=2048)
        gemm_bt_bf16<<<dim3(8, 4, 16), 256, 0, stream>>>(
            align_b, 512LL * 2048, encT, 1024LL * 2048, ctx, 512LL * 1024,
            512, 1024, 2048);
    } else {
        // round-1 fallback (needs 32 MiB ws)
        float* dproj = (float*)d_ws;
        gemm_bt_x3<<<dim3(8, 64, 1), 256, 0, stream>>>(
            dec, 0, W, 0, dproj, 0, 8192, 1024, 1024);
        gemm_bt_x3<<<dim3(16, 4, 16), 256, 0, stream>>>(
            dproj, 512LL * 1024, enc, 2048LL * 1024, align, 512LL * 2048, 512, 2048, 1024);
        softmax_rows<<<8192, 256, 0, stream>>>(align, nullptr);
        gemm_nn_bf16<<<dim3(8, 4, 16), 256, 0, stream>>>(
            align, 512LL * 2048, enc, 2048LL * 1024, ctx, 512LL * 1024, 512, 1024, 2048);
    }
}

// Round 5
// 303.196 us; speedup vs baseline: 1.8519x; 1.0178x over previous
//
#include <hip/hip_runtime.h>
#include <hip/hip_bf16.h>

// LuongAttention: B=16, Tq=512, Tk=2048, D=1024 (fp32 in/out)
// Fast path (ws >= 224 MiB):
//   P0: split_enc_T: enc -> enc_h/enc_l + encT (fused transpose); dec/W splits
//   K1: dproj_h/l = split(dec @ W^T)   gemm_wide<1,1,4>  (128x256, 2-ph dbuf)
//   K2: score = dproj @ enc^T          gemm_wide<1,0,8>  (256x256, 2-ph dbuf)
//   K3: softmax in place + bf16 copy (align_b)
//   K4: ctx = align_b @ encT^T         gemm_wide<0,0,4>  (128x256, 2-ph dbuf)
// Mid path (160..224 MiB): same but encT aliases enc_l -> separate transpose
// after K2 (round-4 ordering). Fallback (<160 MiB): round-1 kernels.
// wa_bias cancels in softmax -> skipped.

typedef float f32x4 __attribute__((ext_vector_type(4)));
typedef __bf16 bf16x8 __attribute__((ext_vector_type(8)));
typedef unsigned short u16x4 __attribute__((ext_vector_type(4)));
typedef unsigned short u16x8 __attribute__((ext_vector_type(8)));

__device__ inline unsigned short f2bf(float f) {
    union { float f; unsigned int u; } v; v.f = f;
    unsigned int r = v.u + 0x7fffu + ((v.u >> 16) & 1u);  // RN-even
    return (unsigned short)(r >> 16);
}
__device__ inline float bf2f(unsigned short h) {
    union { unsigned int u; float f; } v; v.u = ((unsigned int)h) << 16; return v.f;
}

__device__ inline void gload16(const void* g, const void* l) {
    __builtin_amdgcn_global_load_lds(
        (const __attribute__((address_space(1))) unsigned int*)g,
        (__attribute__((address_space(3))) unsigned int*)l, 16, 0, 0);
}

// ---------------- P0: fp32 -> bf16 hi/lo split (elementwise) ----------------
__global__ __launch_bounds__(256)
void split_bf16(const float* __restrict__ x, unsigned short* __restrict__ ho,
                unsigned short* __restrict__ lo, int n8)
{
    int i = blockIdx.x * 256 + threadIdx.x;
    if (i >= n8) return;
    const f32x4* xp = reinterpret_cast<const f32x4*>(x + (size_t)i * 8);
    f32x4 v0 = xp[0], v1 = xp[1];
    u16x8 h, l;
#pragma unroll
    for (int j = 0; j < 4; ++j) {
        unsigned short hh = f2bf(v0[j]);
        h[j] = hh; l[j] = f2bf(v0[j] - bf2f(hh));
        hh = f2bf(v1[j]);
        h[4 + j] = hh; l[4 + j] = f2bf(v1[j] - bf2f(hh));
    }
    *reinterpret_cast<u16x8*>(ho + (size_t)i * 8) = h;
    *reinterpret_cast<u16x8*>(lo + (size_t)i * 8) = l;
}

// ---- P0 fused: enc fp32 -> enc_h, enc_l (row-major) + encT (hi transposed) -
// enc [16][2048][1024]; encT [16][1024][2048]. 64x64 tiles.
__global__ __launch_bounds__(256)
void split_enc_T(const float* __restrict__ enc, unsigned short* __restrict__ eh,
                 unsigned short* __restrict__ el, unsigned short* __restrict__ eT)
{
    __shared__ unsigned short t[64][72];
    const int b = blockIdx.z;
    const int kb = blockIdx.x * 64;   // Tk
    const int db = blockIdx.y * 64;   // D
    const int r = threadIdx.x >> 4;          // 0..15
    const int c0 = (threadIdx.x & 15) * 4;   // 0..60
    const float* ip = enc + ((size_t)b * 2048 + kb) * 1024 + db;
#pragma unroll
    for (int it = 0; it < 4; ++it) {
        int row = it * 16 + r;
        f32x4 v = *reinterpret_cast<const f32x4*>(ip + (size_t)row * 1024 + c0);
        u16x4 h, l;
#pragma unroll
        for (int j = 0; j < 4; ++j) {
            h[j] = f2bf(v[j]); l[j] = f2bf(v[j] - bf2f(h[j]));
        }
        size_t go = ((size_t)b * 2048 + kb + row) * 1024 + db + c0;
        *reinterpret_cast<u16x4*>(eh + go) = h;
        *reinterpret_cast<u16x4*>(el + go) = l;
#pragma unroll
        for (int j = 0; j < 4; ++j) t[c0 + j][row] = h[j];
    }
    __syncthreads();
    const int d = threadIdx.x >> 2;   // 0..63 (D within tile)
    const int ch = threadIdx.x & 3;   // k-chunk of 16
    unsigned short* op = eT + ((size_t)b * 1024 + db + d) * 2048 + kb + ch * 16;
    u16x8 w0, w1;
#pragma unroll
    for (int j = 0; j < 8; ++j) { w0[j] = t[d][ch * 16 + j]; w1[j] = t[d][ch * 16 + 8 + j]; }
    *reinterpret_cast<u16x8*>(op) = w0;
    *reinterpret_cast<u16x8*>(op + 8) = w1;
}

// ------- T: bf16 transpose  in [16][2048][1024] -> out [16][1024][2048] -----
// (mid-path only, when encT must alias enc_l and run after K2)
__global__ __launch_bounds__(256)
void transpose_bf16(const unsigned short* __restrict__ in, unsigned short* __restrict__ out)
{
    __shared__ unsigned short t[64][65];
    const int b = blockIdx.z;
    const int kb = blockIdx.x * 64;
    const int db = blockIdx.y * 64;
    const unsigned short* ip = in + ((size_t)b * 2048 + kb) * 1024 + db;
    unsigned short* op = out + ((size_t)b * 1024 + db) * 2048 + kb;
    const int r = threadIdx.x >> 3;
    const int c0 = (threadIdx.x & 7) * 8;
#pragma unroll
    for (int h = 0; h < 2; ++h) {
        u16x8 v = *reinterpret_cast<const u16x8*>(ip + (size_t)(r + h * 32) * 1024 + c0);
#pragma unroll
        for (int j = 0; j < 8; ++j) t[c0 + j][r + h * 32] = v[j];
    }
    __syncthreads();
#pragma unroll
    for (int h = 0; h < 2; ++h) {
        int orow = r + h * 32;
        u16x8 v = *reinterpret_cast<const u16x8*>(&t[orow][c0]);
        *reinterpret_cast<u16x8*>(op + (size_t)orow * 2048 + c0) = v;
    }
}

// ========== generalized wide BT GEMM (round-4 K2 structure, templated) ======
// C = A @ B^T (X3: (Ah+Al)@(Bh+Bl)^T with hi*hi+hi*lo+lo*hi). A [M,K] bf16
// planes, B [N,K] bf16 planes, K%32==0. BM=32*AM, BN=256, BK=32, 8 waves
// (2 rows x 4 cols), wave-tile (16*AM)x64, acc[AM][4].
// LDS rows 64B, phys slot = (kc + (row>>1)) & 3 (8 rows cover all bank-quads).
// Linear LDS dest (gload_lds), pre-swizzled global source. 2-phase dbuf:
// stage(next) issued before compute(cur), one __syncthreads per K-step.
// Grid: 1D nwg = (M/BM)*(N/256)*batch (nwg%8==0), XCD-swizzled.
// OUTMODE 0: fp32 C. OUTMODE 1: bf16 hi/lo split -> Ch, Cl.
template<int X3, int OUTMODE, int AM>
__global__ __launch_bounds__(512, 2)
void gemm_wide(const unsigned short* __restrict__ Ah, const unsigned short* __restrict__ Al,
               long long sA,
               const unsigned short* __restrict__ Bh, const unsigned short* __restrict__ Bl,
               long long sB,
               float* __restrict__ C, unsigned short* __restrict__ Ch,
               unsigned short* __restrict__ Cl, long long sC,
               int M, int N, int K)
{
    constexpr int BM  = 32 * AM;
    constexpr int LVL = (BM + 256) * 32;          // u16 elems per level
    constexpr int BUF = LVL * (X3 ? 2 : 1);
    constexpr int NI  = (BM + 256) / 128;         // staging iters per level
    __shared__ unsigned short smem[2 * BUF];

    const int tid = threadIdx.x, lane = tid & 63, wave = tid >> 6;

    // XCD swizzle + batch decode (m-fastest)
    const int nwg = gridDim.x;
    int orig = (blockIdx.x & 7) * (nwg >> 3) + (blockIdx.x >> 3);
    const int mb = M / BM, nb = N >> 8, bpb = mb * nb;
    const int z = orig / bpb, rem = orig - z * bpb;
    const int bm = (rem % mb) * BM, bn = (rem / mb) << 8;

    Ah += (size_t)z * sA; Bh += (size_t)z * sB;
    if (X3) { Al += (size_t)z * sA; Bl += (size_t)z * sB; }

    // staging geometry: slot c = i*512+tid -> row=c>>2, phys slot s=c&3 holds
    // global chunk g = (s - (row>>1)) & 3.  A rows [0,BM), B rows [BM,BM+256).
    const unsigned short* srcH[NI];
    const unsigned short* srcL[NI];
    int dst[NI];
#pragma unroll
    for (int i = 0; i < NI; ++i) {
        int c = i * 512 + tid, row = c >> 2, s = c & 3;
        int isA = row < BM;
        int r = isA ? row : row - BM;
        int g = (s + 4 - ((r >> 1) & 3)) & 3;
        srcH[i] = (isA ? Ah + (size_t)(bm + r) * K : Bh + (size_t)(bn + r) * K) + g * 8;
        if (X3) srcL[i] = (isA ? Al + (size_t)(bm + r) * K : Bl + (size_t)(bn + r) * K) + g * 8;
        dst[i] = row * 32 + s * 8;
    }

    const int kcL = lane >> 4, fr = lane & 15;
    const int wrow = (wave >> 2) * (16 * AM);
    const int wcol = (wave & 3) * 64;

    f32x4 acc[AM][4] = {};
    const int nt = K >> 5;
    int cur = 0;

    {   // prologue: stage K-tile 0 into buf 0
#pragma unroll
        for (int i = 0; i < NI; ++i) {
            gload16(srcH[i], smem + dst[i]);
            if constexpr (X3) gload16(srcL[i], smem + LVL + dst[i]);
        }
    }
    __syncthreads();

    for (int t = 0; t < nt; ++t) {
        if (t + 1 < nt) {   // issue next-tile stage BEFORE compute (2-phase)
            const int kt = (t + 1) << 5;
            unsigned short* bx = smem + (cur ^ 1) * BUF;
#pragma unroll
            for (int i = 0; i < NI; ++i) {
                gload16(srcH[i] + kt, bx + dst[i]);
                if constexpr (X3) gload16(srcL[i] + kt, bx + LVL + dst[i]);
            }
        }
        const unsigned short* base = smem + cur * BUF;
        bf16x8 bh[4], bl[4];
#pragma unroll
        for (int n = 0; n < 4; ++n) {
            int rowB = wcol + n * 16 + fr;
            int off = BM * 32 + rowB * 32 + (((kcL + (rowB >> 1)) & 3) << 3);
            bh[n] = *reinterpret_cast<const bf16x8*>(base + off);
            if constexpr (X3) bl[n] = *reinterpret_cast<const bf16x8*>(base + LVL + off);
        }
#pragma unroll
        for (int m = 0; m < AM; ++m) {
            int rowA = wrow + m * 16 + fr;
            int off = rowA * 32 + (((kcL + (rowA >> 1)) & 3) << 3);
            bf16x8 ah = *reinterpret_cast<const bf16x8*>(base + off);
            bf16x8 al;
            if constexpr (X3) al = *reinterpret_cast<const bf16x8*>(base + LVL + off);
#pragma unroll
            for (int n = 0; n < 4; ++n) {
                acc[m][n] = __builtin_amdgcn_mfma_f32_16x16x32_bf16(ah, bh[n], acc[m][n], 0, 0, 0);
                if constexpr (X3) {
                    acc[m][n] = __builtin_amdgcn_mfma_f32_16x16x32_bf16(ah, bl[n], acc[m][n], 0, 0, 0);
                    acc[m][n] = __builtin_amdgcn_mfma_f32_16x16x32_bf16(al, bh[n], acc[m][n], 0, 0, 0);
                }
            }
        }
        __syncthreads();   // drains vmcnt: next buf staged; reads of cur done
        cur ^= 1;
    }

    // C/D layout: col = lane&15, row = (lane>>4)*4 + j  [HW-verified]
    if constexpr (OUTMODE == 0) {
        float* Cz = C + (size_t)z * sC;
#pragma unroll
        for (int m = 0; m < AM; ++m)
#pragma unroll
            for (int j = 0; j < 4; ++j) {
                int grow = bm + wrow + m * 16 + (lane >> 4) * 4 + j;
                float* cr = Cz + (size_t)grow * N + bn + wcol + fr;
#pragma unroll
                for (int n = 0; n < 4; ++n) cr[n * 16] = acc[m][n][j];
            }
    } else {
        unsigned short* Chz = Ch + (size_t)z * sC;
        unsigned short* Clz = Cl + (size_t)z * sC;
#pragma unroll
        for (int m = 0; m < AM; ++m)
#pragma unroll
            for (int j = 0; j < 4; ++j) {
                int grow = bm + wrow + m * 16 + (lane >> 4) * 4 + j;
                size_t rb = (size_t)grow * N + bn + wcol + fr;
#pragma unroll
                for (int n = 0; n < 4; ++n) {
                    float v = acc[m][n][j];
                    unsigned short hh = f2bf(v);
                    Chz[rb + n * 16] = hh;
                    Clz[rb + n * 16] = f2bf(v - bf2f(hh));
                }
            }
    }
}

// ---------------- softmax rows (2048 cols) + optional bf16 copy -------------
__global__ __launch_bounds__(256)
void softmax_rows(float* __restrict__ P, unsigned short* __restrict__ albf)
{
    __shared__ float redm[4], reds[4];
    float* p = P + (size_t)blockIdx.x * 2048;
    const int tid = threadIdx.x, lane = tid & 63, wave = tid >> 6;

    f32x4 v0 = *reinterpret_cast<const f32x4*>(p + tid * 4);
    f32x4 v1 = *reinterpret_cast<const f32x4*>(p + 1024 + tid * 4);

    float mx = fmaxf(fmaxf(fmaxf(v0[0], v0[1]), fmaxf(v0[2], v0[3])),
                     fmaxf(fmaxf(v1[0], v1[1]), fmaxf(v1[2], v1[3])));
#pragma unroll
    for (int o = 32; o; o >>= 1) mx = fmaxf(mx, __shfl_xor(mx, o));
    if (lane == 0) redm[wave] = mx;
    __syncthreads();
    mx = fmaxf(fmaxf(redm[0], redm[1]), fmaxf(redm[2], redm[3]));

    float s = 0.f;
#pragma unroll
    for (int j = 0; j < 4; ++j) { v0[j] = __expf(v0[j] - mx); s += v0[j]; }
#pragma unroll
    for (int j = 0; j < 4; ++j) { v1[j] = __expf(v1[j] - mx); s += v1[j]; }
#pragma unroll
    for (int o = 32; o; o >>= 1) s += __shfl_xor(s, o);
    if (lane == 0) reds[wave] = s;
    __syncthreads();
    s = reds[0] + reds[1] + reds[2] + reds[3];

    const float inv = 1.0f / s;
#pragma unroll
    for (int j = 0; j < 4; ++j) { v0[j] *= inv; v1[j] *= inv; }
    *reinterpret_cast<f32x4*>(p + tid * 4) = v0;
    *reinterpret_cast<f32x4*>(p + 1024 + tid * 4) = v1;

    if (albf) {
        unsigned short* ab = albf + (size_t)blockIdx.x * 2048;
        u16x4 h0, h1;
#pragma unroll
        for (int j = 0; j < 4; ++j) { h0[j] = f2bf(v0[j]); h1[j] = f2bf(v1[j]); }
        *reinterpret_cast<u16x4*>(ab + tid * 4) = h0;
        *reinterpret_cast<u16x4*>(ab + 1024 + tid * 4) = h1;
    }
}

// ======================= round-1 fallback kernels ===========================
__device__ inline int tile_byte(int row, int kElem) {
    int chunk = kElem >> 3;
    return row * 128 + ((chunk ^ (row & 7)) << 4) + ((kElem & 7) << 1);
}

__global__ __launch_bounds__(256, 2)
void gemm_bt_x3(const float* __restrict__ A, long long sA,
                const float* __restrict__ Bt, long long sB,
                float* __restrict__ C, long long sC,
                int M, int N, int K)
{
    __shared__ unsigned short Ah[128 * 64], Al[128 * 64];
    __shared__ unsigned short Bh[128 * 64], Bl[128 * 64];

    const int tid = threadIdx.x, lane = tid & 63, wave = tid >> 6;
    const int wr = (wave >> 1) * 64, wc = (wave & 1) * 64;
    const int bm = blockIdx.y * 128, bn = blockIdx.x * 128;
    A += (size_t)blockIdx.z * sA;
    Bt += (size_t)blockIdx.z * sB;
    C += (size_t)blockIdx.z * sC;

    f32x4 acc[4][4] = {};

    for (int kt = 0; kt < K; kt += 64) {
#pragma unroll
        for (int i = 0; i < 8; ++i) {
            int idx = tid + i * 256;
            int row = idx >> 4, f4 = idx & 15;
            f32x4 va = *reinterpret_cast<const f32x4*>(A + (size_t)(bm + row) * K + kt + f4 * 4);
            f32x4 vb = *reinterpret_cast<const f32x4*>(Bt + (size_t)(bn + row) * K + kt + f4 * 4);
            u16x4 ah, al, bh, bl;
#pragma unroll
            for (int j = 0; j < 4; ++j) {
                unsigned short h = f2bf(va[j]);
                ah[j] = h; al[j] = f2bf(va[j] - bf2f(h));
                h = f2bf(vb[j]);
                bh[j] = h; bl[j] = f2bf(vb[j] - bf2f(h));
            }
            int off = tile_byte(row, f4 * 4);
            *reinterpret_cast<u16x4*>((char*)Ah + off) = ah;
            *reinterpret_cast<u16x4*>((char*)Al + off) = al;
            *reinterpret_cast<u16x4*>((char*)Bh + off) = bh;
            *reinterpret_cast<u16x4*>((char*)Bl + off) = bl;
        }
        __syncthreads();
#pragma unroll
        for (int kk = 0; kk < 2; ++kk) {
            bf16x8 a_h[4], a_l[4], b_h[4], b_l[4];
            const int kbase = kk * 32 + (lane >> 4) * 8;
#pragma unroll
            for (int m = 0; m < 4; ++m) {
                int off = tile_byte(wr + m * 16 + (lane & 15), kbase);
                a_h[m] = *reinterpret_cast<const bf16x8*>((char*)Ah + off);
                a_l[m] = *reinterpret_cast<const bf16x8*>((char*)Al + off);
            }
#pragma unroll
            for (int n = 0; n < 4; ++n) {
                int off = tile_byte(wc + n * 16 + (lane & 15), kbase);
                b_h[n] = *reinterpret_cast<const bf16x8*>((char*)Bh + off);
                b_l[n] = *reinterpret_cast<const bf16x8*>((char*)Bl + off);
            }
#pragma unroll
            for (int m = 0; m < 4; ++m)
#pragma unroll
                for (int n = 0; n < 4; ++n) {
                    acc[m][n] = __builtin_amdgcn_mfma_f32_16x16x32_bf16(a_h[m], b_h[n], acc[m][n], 0, 0, 0);
                    acc[m][n] = __builtin_amdgcn_mfma_f32_16x16x32_bf16(a_h[m], b_l[n], acc[m][n], 0, 0, 0);
                    acc[m][n] = __builtin_amdgcn_mfma_f32_16x16x32_bf16(a_l[m], b_h[n], acc[m][n], 0, 0, 0);
                }
        }
        __syncthreads();
    }
#pragma unroll
    for (int m = 0; m < 4; ++m)
#pragma unroll
        for (int j = 0; j < 4; ++j) {
            int grow = bm + wr + m * 16 + (lane >> 4) * 4 + j;
            float* cr = C + (size_t)grow * N + bn + wc + (lane & 15);
#pragma unroll
            for (int n = 0; n < 4; ++n) cr[n * 16] = acc[m][n][j];
        }
}

__global__ __launch_bounds__(256, 2)
void gemm_nn_bf16(const float* __restrict__ A, long long sA,
                  const float* __restrict__ Bn, long long sB,
                  float* __restrict__ C, long long sC,
                  int M, int N, int K)
{
    __shared__ unsigned short As[128 * 64];
    __shared__ unsigned short Bs[64 * 130];

    const int tid = threadIdx.x, lane = tid & 63, wave = tid >> 6;
    const int wr = (wave >> 1) * 64, wc = (wave & 1) * 64;
    const int bm = blockIdx.y * 128, bn = blockIdx.x * 128;
    A += (size_t)blockIdx.z * sA;
    Bn += (size_t)blockIdx.z * sB;
    C += (size_t)blockIdx.z * sC;

    f32x4 acc[4][4] = {};

    for (int kt = 0; kt < K; kt += 64) {
#pragma unroll
        for (int i = 0; i < 8; ++i) {
            int idx = tid + i * 256;
            int row = idx >> 4, f4 = idx & 15;
            f32x4 va = *reinterpret_cast<const f32x4*>(A + (size_t)(bm + row) * K + kt + f4 * 4);
            u16x4 h;
#pragma unroll
            for (int j = 0; j < 4; ++j) h[j] = f2bf(va[j]);
            *reinterpret_cast<u16x4*>((char*)As + tile_byte(row, f4 * 4)) = h;
        }
#pragma unroll
        for (int i = 0; i < 8; ++i) {
            int idx = tid + i * 256;
            int krow = idx >> 5, f4 = idx & 31;
            f32x4 vb = *reinterpret_cast<const f32x4*>(Bn + (size_t)(kt + krow) * N + bn + f4 * 4);
            unsigned int p0 = (unsigned int)f2bf(vb[0]) | ((unsigned int)f2bf(vb[1]) << 16);
            unsigned int p1 = (unsigned int)f2bf(vb[2]) | ((unsigned int)f2bf(vb[3]) << 16);
            unsigned int* bp = reinterpret_cast<unsigned int*>(&Bs[krow * 130 + f4 * 4]);
            bp[0] = p0; bp[1] = p1;
        }
        __syncthreads();
#pragma unroll
        for (int kk = 0; kk < 2; ++kk) {
            bf16x8 a[4], b[4];
            const int kbase = kk * 32 + (lane >> 4) * 8;
#pragma unroll
            for (int m = 0; m < 4; ++m)
                a[m] = *reinterpret_cast<const bf16x8*>((char*)As + tile_byte(wr + m * 16 + (lane & 15), kbase));
#pragma unroll
            for (int n = 0; n < 4; ++n) {
                int col = wc + n * 16 + (lane & 15);
                union { unsigned short u[8]; bf16x8 v; } t;
#pragma unroll
                for (int j = 0; j < 8; ++j) t.u[j] = Bs[(kbase + j) * 130 + col];
                b[n] = t.v;
            }
#pragma unroll
            for (int m = 0; m < 4; ++m)
#pragma unroll
                for (int n = 0; n < 4; ++n)
                    acc[m][n] = __builtin_amdgcn_mfma_f32_16x16x32_bf16(a[m], b[n], acc[m][n], 0, 0, 0);
        }
        __syncthreads();
    }
#pragma unroll
    for (int m = 0; m < 4; ++m)
#pragma unroll
        for (int j = 0; j < 4; ++j) {
            int grow = bm + wr + m * 16 + (lane >> 4) * 4 + j;
            float* cr = C + (size_t)grow * N + bn + wc + (lane & 15);
#pragma unroll
            for (int n = 0; n < 4; ++n) cr[n * 16] = acc[m][n][j];
        }
}

// ============================================================================
extern "C" void kernel_launch(void* const* d_in, const int* in_sizes, int n_in,
                              void* d_out, int out_size, void* d_ws, size_t ws_size,
                              hipStream_t stream)
{
    (void)in_sizes; (void)n_in; (void)out_size;
    const float* dec = (const float*)d_in[0];   // [16,512,1024]
    const float* enc = (const float*)d_in[1];   // [16,2048,1024]
    const float* W   = (const float*)d_in[2];   // [1024,1024]

    float* ctx   = (float*)d_out;                            // [16,512,1024]
    float* align = (float*)d_out + (size_t)16 * 512 * 1024;  // [16,512,2048]

    const size_t MiB = 1048576ULL;
    const size_t NEED_FUSED = 224 * MiB;   // enc_h + enc_l + encT + align_b
    const size_t NEED_FAST  = 160 * MiB;   // enc_h + enc_l(/encT alias) + align_b

    if (ws_size >= NEED_FAST) {
        const bool fused = (ws_size >= NEED_FUSED);
        unsigned short* enc_h   = (unsigned short*)d_ws;             // 64 MiB
        unsigned short* enc_l   = enc_h + 33554432ULL;               // 64 MiB
        unsigned short* encT    = fused ? (enc_l + 33554432ULL)      // own 64 MiB
                                        : enc_l;                     // alias after K2
        unsigned short* align_b = fused ? (encT + 33554432ULL)
                                        : (enc_l + 33554432ULL);     // 32 MiB
        unsigned short* dproj_h = (unsigned short*)d_out;            // ctx region (dead)
        unsigned short* dproj_l = dproj_h + 8388608ULL;
        unsigned short* dec_h   = (unsigned short*)align;            // align region (dead)
        unsigned short* dec_l   = dec_h + 8388608ULL;
        unsigned short* W_h     = dec_l + 8388608ULL;
        unsigned short* W_l     = W_h + 1048576ULL;

        // P0: splits (+ fused transpose when encT has its own region)
        if (fused)
            split_enc_T<<<dim3(32, 16, 16), 256, 0, stream>>>(enc, enc_h, enc_l, encT);
        else
            split_bf16<<<16384, 256, 0, stream>>>(enc, enc_h, enc_l, 4194304);
        split_bf16<<<4096, 256, 0, stream>>>(dec, dec_h, dec_l, 1048576);
        split_bf16<<<512, 256, 0, stream>>>(W, W_h, W_l, 131072);

        // K1: dproj = dec @ W^T  (M=8192, N=1024, K=1024) -> bf16 split planes
        // 128x256 tiles: grid 64*4 = 256 blocks
        gemm_wide<1, 1, 4><<<256, 512, 0, stream>>>(
            dec_h, dec_l, 0, W_h, W_l, 0,
            nullptr, dproj_h, dproj_l, 0, 8192, 1024, 1024);

        // K2: score = dproj @ enc^T per batch (M=512, N=2048, K=1024) -> align
        // 256x256 tiles: grid 2*8*16 = 256 blocks
        gemm_wide<1, 0, 8><<<256, 512, 0, stream>>>(
            dproj_h, dproj_l, 512LL * 1024, enc_h, enc_l, 2048LL * 1024,
            align, nullptr, nullptr, 512LL * 2048, 512, 2048, 1024);

        // mid path: transpose enc_h into enc_l region (dead after K2)
        if (!fused)
            transpose_bf16<<<dim3(32, 16, 16), 256, 0, stream>>>(enc_h, encT);

        // K3: softmax + bf16 copy
        softmax_rows<<<8192, 256, 0, stream>>>(align, align_b);

        // K4: ctx = align_b @ encT^T per batch (M=512, N=1024, K=2048)
        // 128x256 tiles: grid 4*4*16 = 256 blocks
        gemm_wide<0, 0, 4><<<256, 512, 0, stream>>>(
            align_b, nullptr, 512LL * 2048, encT, nullptr, 1024LL * 2048,
            ctx, nullptr, nullptr, 512LL * 1024, 512, 1024, 2048);
    } else {
        // round-1 fallback (needs 32 MiB ws)
        float* dproj = (float*)d_ws;
        gemm_bt_x3<<<dim3(8, 64, 1), 256, 0, stream>>>(
            dec, 0, W, 0, dproj, 0, 8192, 1024, 1024);
        gemm_bt_x3<<<dim3(16, 4, 16), 256, 0, stream>>>(
            dproj, 512LL * 1024, enc, 2048LL * 1024, align, 512LL * 2048, 512, 2048, 1024);
        softmax_rows<<<8192, 256, 0, stream>>>(align, nullptr);
        gemm_nn_bf16<<<dim3(8, 4, 16), 256, 0, stream>>>(
            align, 512LL * 2048, enc, 2048LL * 1024, ctx, 512LL * 1024, 512, 1024, 2048);
    }
}